// Round 5
// baseline (703.620 us; speedup 1.0000x reference)
//
#include <hip/hip_runtime.h>
#include <hip/hip_bf16.h>

typedef __hip_bfloat16 bf16;
typedef unsigned short ush;
typedef short s16x8 __attribute__((ext_vector_type(8)));
typedef float f32x4 __attribute__((ext_vector_type(4)));

#define DEV __device__ __forceinline__

DEV float sigmoid_f(float x) { return 1.f / (1.f + __expf(-x)); }
DEV float tanh_f(float x) { return 1.f - 2.f / (__expf(2.f * x) + 1.f); }

DEV float u2f(ush u) { unsigned int v = ((unsigned int)u) << 16; float f; __builtin_memcpy(&f, &v, 4); return f; }
DEV ush f2u(float f) { bf16 h = __float2bfloat16(f); ush u; __builtin_memcpy(&u, &h, 2); return u; }

DEV f32x4 MFMA(s16x8 a, s16x8 b, f32x4 c) {
  return __builtin_amdgcn_mfma_f32_16x16x32_bf16(a, b, c, 0, 0, 0);
}

// swizzled element index within a [rows][32] bf16 chunk: 16B blocks XOR'd by (row>>1)&3
DEV int swz_idx(int row, int kk) { return row * 32 + (((kk >> 3) ^ ((row >> 1) & 3)) << 3) + (kk & 7); }
DEV int swz_blk(int row, int blk) { return row * 32 + ((blk ^ ((row >> 1) & 3)) << 3); }

// ---------------------------------------------------------------------------
// Constants: N=4096 graphs, K=8 nodes, n_in=14, H=128, k=3 iters. Inputs fp32.
// xh buffer: [32768][144] bf16 = [towers(14), pad(2), h(128)]
// eh buffer: [262144][128] bf16
// Edge GRU factorization: gi(edge i,j) = Wa.xh_i + Wb.xh_j  (Wa=Wih[:, :142],
// Wb=Wih[:,142:284]). Pq[node][768] = [P(384) | Q(384)], P = xh@Wa^T + bias
// fold, Q = xh@Wb^T. Edge kernel then only needs the h-phase GEMM (K=128).
// ---------------------------------------------------------------------------

__global__ __launch_bounds__(256) void prep_xh_t(const float* __restrict__ towers, ush* __restrict__ xh) {
  const int idx = blockIdx.x * 256 + threadIdx.x;   // 32768*16
  if (idx >= 32768 * 16) return;
  const int row = idx >> 4, kk = idx & 15;
  xh[row * 144 + kk] = f2u(kk < 14 ? towers[row * 14 + kk] : 0.f);
}

// WPQ[5 chunks][768][32] bf16, linear (direct-global B). n<384: P gates (Wa), n>=384: Q (Wb).
// FIXED (r4 bug): chunk = 768*32 = 24576 elems (was >>14 = /16384); gate decode
// m = n - 384*half (was (n&383)>>7 which scrambles since 384 != pow2).
__global__ __launch_bounds__(256) void prep_WPQ(const float* __restrict__ Wih, ush* __restrict__ dst) {
  const int idx = blockIdx.x * 256 + threadIdx.x;   // 5*768*32 = 122880
  if (idx >= 5 * 768 * 32) return;
  const int ck = idx / 24576, rem = idx % 24576, n = rem >> 5, kk = rem & 31;
  const int k = ck * 32 + kk;
  const int half = (n >= 384);
  const int m = n - half * 384;                     // 0..383 within half
  const int g = m >> 7, c = m & 127;                // gate r,z,n1 ; col
  const int row = g * 128 + c;
  int col = -1;
  if (k < 14)                  col = k;             // tower part
  else if (k >= 16 && k < 144) col = k - 2;         // h part (Wih col 14..141)
  if (half && col >= 0)        col += 142;          // Wb offset
  const float w = (col >= 0) ? Wih[row * 284 + col] : 0.f;
  dst[idx] = f2u(w);
}

// WTh[4 chunks][384][32] bf16 linear: h-phase gates r,z,n2 from M_Whh
// FIXED (r4 bug): chunk = 384*32 = 12288 elems (was >>13 = /8192).
__global__ __launch_bounds__(256) void prep_WTh(const float* __restrict__ Whh, ush* __restrict__ dst) {
  const int idx = blockIdx.x * 256 + threadIdx.x;   // 4*384*32 = 49152
  if (idx >= 4 * 384 * 32) return;
  const int ck = idx / 12288, rem = idx % 12288, n = rem >> 5, kk = rem & 31;
  const int g = n >> 7, c = n & 127;                // g 0,1,2 -> Whh rows r,z,n
  dst[idx] = f2u(Whh[(g * 128 + c) * 128 + ck * 32 + kk]);
}

__global__ __launch_bounds__(256) void prep_WTu(const float* __restrict__ Wih, const float* __restrict__ Whh,
                                                ush* __restrict__ dst) {
  const int idx = blockIdx.x * 256 + threadIdx.x;   // 9*512*32 = 147456
  if (idx >= 9 * 512 * 32) return;
  const int ck = idx >> 14, n = (idx >> 5) & 511, kk = idx & 31;   // chunk 512*32=16384: >>14 OK
  const int k = ck * 32 + kk, gate = n >> 7, c = n & 127;
  float w = 0.f;
  const int row = (gate == 0) ? c : (gate == 1) ? 128 + c : 256 + c;
  if (k < 160) {            // x region -> U_Wih (142 cols: t, edges)
    int col = -1;
    if (k < 16)        { if (k < 14) col = k; }
    else if (k < 144)  col = 14 + (k - 16);
    if (gate != 3 && col >= 0) w = Wih[row * 142 + col];
  } else {                  // h region -> U_Whh
    if (gate != 2) w = Whh[row * 128 + (k - 160)];
  }
  dst[ck * 16384 + swz_idx(n, kk)] = f2u(w);
}

// mode 0: 128x14 (En_W1, K pad 32); mode 1: 128x28 pair (Ee_W1); mode 2: 128x128 dense
__global__ __launch_bounds__(256) void prep_wb(const float* __restrict__ W, ush* __restrict__ dst,
                                               int mode, int nelem) {
  const int idx = blockIdx.x * 256 + threadIdx.x;
  if (idx >= nelem) return;
  const int ck = idx >> 12, n = (idx >> 5) & 127, kk = idx & 31;   // chunk 128*32=4096: >>12 OK
  float w = 0.f;
  if (mode == 2)      w = W[n * 128 + ck * 32 + kk];
  else if (mode == 0) { if (kk < 14) w = W[n * 14 + kk]; }
  else {
    int col = (kk < 16) ? (kk < 14 ? kk : -1) : (kk < 30 ? 14 + (kk - 16) : -1);
    if (col >= 0) w = W[n * 28 + col];
  }
  dst[ck * 4096 + swz_idx(n, kk)] = f2u(w);
}

__global__ __launch_bounds__(256) void prep_bias4(const float* __restrict__ bih, const float* __restrict__ bhh,
                                                  float* __restrict__ dst) {
  const int idx = blockIdx.x * 256 + threadIdx.x;
  if (idx >= 512) return;
  const int g = idx >> 7, c = idx & 127;
  float v;
  if (g == 0)      v = bih[c] + bhh[c];
  else if (g == 1) v = bih[128 + c] + bhh[128 + c];
  else if (g == 2) v = bih[256 + c];
  else             v = bhh[256 + c];
  dst[idx] = v;
}

// ---------------------------------------------------------------------------
// PQ GEMM: Pq[32768][768] = xh @ [Wa|Wb]^T (+bias fold on P half).
// Block = 64 rows x 384 cols (blockIdx.y = P/Q half); wave = 96 cols.
// ---------------------------------------------------------------------------
template<class PT>
__global__ __launch_bounds__(256, 2) void pq_mfma(
    const ush* __restrict__ xh, const ush* __restrict__ WPQ,
    const float* __restrict__ biasM, PT* __restrict__ Pq)
{
  __shared__ ush As[5 * 64 * 32];
  const int t = threadIdx.x, lane = t & 63, w = t >> 6;
  const int rowBase = blockIdx.x * 64, half = blockIdx.y;
  const int gm = t >> 2, gb = t & 3, grow = rowBase + gm;

  #pragma unroll
  for (int ck = 0; ck < 5; ++ck) {
    const int k0 = ck * 32 + gb * 8;
    s16x8 v;
    #pragma unroll
    for (int z = 0; z < 8; ++z) v[z] = 0;
    if (k0 < 144) v = *(const s16x8*)(xh + grow * 144 + k0);
    *(s16x8*)&As[ck * 2048 + swz_blk(gm, gb)] = v;
  }
  __syncthreads();

  f32x4 acc[6][4];
  #pragma unroll
  for (int tl = 0; tl < 6; ++tl)
    #pragma unroll
    for (int rt = 0; rt < 4; ++rt) {
      #pragma unroll
      for (int q = 0; q < 4; ++q) acc[tl][rt][q] = 0.f;
    }

  for (int ck = 0; ck < 5; ++ck) {
    s16x8 af[4];
    #pragma unroll
    for (int rt = 0; rt < 4; ++rt)
      af[rt] = *(const s16x8*)&As[ck * 2048 + swz_blk(rt * 16 + (lane & 15), lane >> 4)];
    #pragma unroll
    for (int tl = 0; tl < 6; ++tl) {
      const int n = w * 96 + tl * 16 + (lane & 15);
      const s16x8 bf = *(const s16x8*)&WPQ[(ck * 768 + half * 384 + n) * 32 + (lane >> 4) * 8];
      #pragma unroll
      for (int rt = 0; rt < 4; ++rt) acc[tl][rt] = MFMA(af[rt], bf, acc[tl][rt]);
    }
  }

  #pragma unroll
  for (int tl = 0; tl < 6; ++tl) {
    const int col = w * 96 + tl * 16 + (lane & 15);
    const float bv = half ? 0.f : biasM[col];
    #pragma unroll
    for (int rt = 0; rt < 4; ++rt) {
      #pragma unroll
      for (int q = 0; q < 4; ++q) {
        const int row = rowBase + rt * 16 + (lane >> 4) * 4 + q;
        const float v = acc[tl][rt][q] + bv;
        if (sizeof(PT) == 4) ((float*)Pq)[row * 768 + half * 384 + col] = v;
        else                 ((ush*)Pq)[row * 768 + half * 384 + col] = f2u(v);
      }
    }
  }
}

// ---------------------------------------------------------------------------
// Edge GRU: block = 1 graph = 64 edge rows. h-phase GEMM (K=128) + P/Q lookup.
// B fragments direct global->register (L2-resident, identical for all blocks).
// ---------------------------------------------------------------------------
template<class PT>
__global__ __launch_bounds__(256, 2) void edge_mfma(
    ush* __restrict__ eh, const ush* __restrict__ WTh,
    const PT* __restrict__ Pq, const float* __restrict__ biasM)
{
  __shared__ ush As[4 * 64 * 32];     // e_h 64x128 swizzled
  __shared__ float PQl[8 * 776];      // P|Q rows for this graph's 8 nodes (pad 776)
  const int t = threadIdx.x, lane = t & 63, w = t >> 6;
  const int n = blockIdx.x, rowBase = n * 64;

  {
    const int gm = t >> 2, gb = t & 3;
    #pragma unroll
    for (int ck = 0; ck < 4; ++ck) {
      const s16x8 v = *(const s16x8*)(eh + (rowBase + gm) * 128 + ck * 32 + gb * 8);
      *(s16x8*)&As[ck * 2048 + swz_blk(gm, gb)] = v;
    }
  }
  if (sizeof(PT) == 4) {
    #pragma unroll
    for (int ii = 0; ii < 6; ++ii) {
      const int idx = t + ii * 256;                  // 1536 float4
      const int r = idx / 192, c4 = (idx % 192) * 4;
      const float4 pv = *(const float4*)((const float*)Pq + (n * 8 + r) * 768 + c4);
      *(float4*)&PQl[r * 776 + c4] = pv;
    }
  } else {
    #pragma unroll
    for (int ii = 0; ii < 3; ++ii) {
      const int idx = t + ii * 256;                  // 768 x 8-elem groups
      const int r = idx / 96, c8 = (idx % 96) * 8;
      const s16x8 pv = *(const s16x8*)((const ush*)Pq + (n * 8 + r) * 768 + c8);
      #pragma unroll
      for (int z = 0; z < 8; ++z) PQl[r * 776 + c8 + z] = u2f((ush)pv[z]);
    }
  }
  __syncthreads();

  f32x4 accR[4][2], accZ[4][2], accN2[4][2];
  #pragma unroll
  for (int rt = 0; rt < 4; ++rt)
    #pragma unroll
    for (int s = 0; s < 2; ++s) {
      #pragma unroll
      for (int q = 0; q < 4; ++q) { accR[rt][s][q] = 0.f; accZ[rt][s][q] = 0.f; accN2[rt][s][q] = 0.f; }
    }

  #pragma unroll
  for (int ck = 0; ck < 4; ++ck) {
    s16x8 af[4];
    #pragma unroll
    for (int rt = 0; rt < 4; ++rt)
      af[rt] = *(const s16x8*)&As[ck * 2048 + swz_blk(rt * 16 + (lane & 15), lane >> 4)];
    #pragma unroll
    for (int s = 0; s < 2; ++s) {
      const int nb = w * 32 + s * 16 + (lane & 15);
      const int ko = (lane >> 4) * 8;
      const s16x8 bR = *(const s16x8*)&WTh[(ck * 384 + nb) * 32 + ko];
      const s16x8 bZ = *(const s16x8*)&WTh[(ck * 384 + 128 + nb) * 32 + ko];
      const s16x8 bN = *(const s16x8*)&WTh[(ck * 384 + 256 + nb) * 32 + ko];
      #pragma unroll
      for (int rt = 0; rt < 4; ++rt) {
        accR[rt][s]  = MFMA(af[rt], bR, accR[rt][s]);
        accZ[rt][s]  = MFMA(af[rt], bZ, accZ[rt][s]);
        accN2[rt][s] = MFMA(af[rt], bN, accN2[rt][s]);
      }
    }
  }

  // epilogue: pre = acc_h + P[i] + Q[j]; h_prev from LDS A tile
  #pragma unroll
  for (int s = 0; s < 2; ++s) {
    const int hcol = w * 32 + s * 16 + (lane & 15);
    const float bN2 = biasM[384 + hcol];
    #pragma unroll
    for (int rt = 0; rt < 4; ++rt) {
      #pragma unroll
      for (int q = 0; q < 4; ++q) {
        const int row = rt * 16 + (lane >> 4) * 4 + q;    // 0..63 local
        const int i = row >> 3, j = row & 7;
        const float preR  = accR[rt][s][q] + PQl[i * 776 + hcol]       + PQl[j * 776 + 384 + hcol];
        const float preZ  = accZ[rt][s][q] + PQl[i * 776 + 128 + hcol] + PQl[j * 776 + 512 + hcol];
        const float preN1 =                  PQl[i * 776 + 256 + hcol] + PQl[j * 776 + 640 + hcol];
        const float hn = accN2[rt][s][q] + bN2;
        const float rg = sigmoid_f(preR);
        const float zg = sigmoid_f(preZ);
        const float nn = tanh_f(preN1 + rg * hn);
        const float hp = u2f(As[(hcol >> 5) * 2048 + swz_idx(row, hcol & 31)]);
        eh[(rowBase + row) * 128 + hcol] = f2u((1.f - zg) * nn + zg * hp);
      }
    }
  }
}

// ---------------------------------------------------------------------------
// Node GRU (MFMA): 64 rows x 512 gate-cols per block.
// ---------------------------------------------------------------------------
__global__ __launch_bounds__(256, 2) void gru_node(
    ush* __restrict__ xh, const ush* __restrict__ eh,
    const ush* __restrict__ WT, const float* __restrict__ bias)
{
  constexpr int NCH = 9, XCH = 5;
  __shared__ ush As[64 * 32];
  __shared__ ush Bs[512 * 32];
  const int t = threadIdx.x, lane = t & 63, w = t >> 6;
  const int rowBase = blockIdx.x * 64;
  const int gm = t >> 2, gb = t & 3, grow = rowBase + gm;

  f32x4 accR[4][2], accZ[4][2], accN1[4][2], accN2[4][2];
  #pragma unroll
  for (int rt = 0; rt < 4; ++rt)
    #pragma unroll
    for (int s = 0; s < 2; ++s) {
      #pragma unroll
      for (int q = 0; q < 4; ++q) { accR[rt][s][q] = 0.f; accZ[rt][s][q] = 0.f; accN1[rt][s][q] = 0.f; accN2[rt][s][q] = 0.f; }
    }

  for (int ck = 0; ck < NCH; ++ck) {
    const ush* wsrc = WT + ck * 16384;
    #pragma unroll
    for (int ii = 0; ii < 8; ++ii) {
      const int o = (t + ii * 256) * 8;
      *(s16x8*)&Bs[o] = *(const s16x8*)&wsrc[o];
    }
    {
      const int k0 = ck * 32 + gb * 8;
      s16x8 v;
      #pragma unroll
      for (int z = 0; z < 8; ++z) v[z] = 0;
      if (k0 < 16)       v = *(const s16x8*)(xh + grow * 144 + k0);
      else if (k0 < 144) {
        const int i = grow & 7;
        if (i < 7) v = *(const s16x8*)(eh + (grow * 8 + i + 1) * 128 + (k0 - 16));
      } else if (k0 >= 160) {
        v = *(const s16x8*)(xh + grow * 144 + 16 + (k0 - 160));
      }
      *(s16x8*)&As[swz_blk(gm, gb)] = v;
    }
    __syncthreads();

    s16x8 af[4];
    #pragma unroll
    for (int rt = 0; rt < 4; ++rt)
      af[rt] = *(const s16x8*)&As[swz_blk(rt * 16 + (lane & 15), lane >> 4)];
    if (ck < XCH) {
      #pragma unroll
      for (int s = 0; s < 2; ++s) {
        const int nb = w * 32 + s * 16 + (lane & 15);
        const s16x8 bR = *(const s16x8*)&Bs[swz_blk(0 * 128 + nb, lane >> 4)];
        const s16x8 bZ = *(const s16x8*)&Bs[swz_blk(1 * 128 + nb, lane >> 4)];
        const s16x8 bN = *(const s16x8*)&Bs[swz_blk(2 * 128 + nb, lane >> 4)];
        #pragma unroll
        for (int rt = 0; rt < 4; ++rt) {
          accR[rt][s]  = MFMA(af[rt], bR, accR[rt][s]);
          accZ[rt][s]  = MFMA(af[rt], bZ, accZ[rt][s]);
          accN1[rt][s] = MFMA(af[rt], bN, accN1[rt][s]);
        }
      }
    } else {
      #pragma unroll
      for (int s = 0; s < 2; ++s) {
        const int nb = w * 32 + s * 16 + (lane & 15);
        const s16x8 bR = *(const s16x8*)&Bs[swz_blk(0 * 128 + nb, lane >> 4)];
        const s16x8 bZ = *(const s16x8*)&Bs[swz_blk(1 * 128 + nb, lane >> 4)];
        const s16x8 bN = *(const s16x8*)&Bs[swz_blk(3 * 128 + nb, lane >> 4)];
        #pragma unroll
        for (int rt = 0; rt < 4; ++rt) {
          accR[rt][s]  = MFMA(af[rt], bR, accR[rt][s]);
          accZ[rt][s]  = MFMA(af[rt], bZ, accZ[rt][s]);
          accN2[rt][s] = MFMA(af[rt], bN, accN2[rt][s]);
        }
      }
    }
    __syncthreads();
  }

  #pragma unroll
  for (int s = 0; s < 2; ++s) {
    const int hcol = w * 32 + s * 16 + (lane & 15);
    const float bR = bias[hcol], bZ = bias[128 + hcol], bN1 = bias[256 + hcol], bN2 = bias[384 + hcol];
    #pragma unroll
    for (int rt = 0; rt < 4; ++rt) {
      #pragma unroll
      for (int q = 0; q < 4; ++q) {
        const int row = rowBase + rt * 16 + (lane >> 4) * 4 + q;
        const float hp = u2f(xh[row * 144 + 16 + hcol]);
        const float rg = sigmoid_f(accR[rt][s][q] + bR);
        const float zg = sigmoid_f(accZ[rt][s][q] + bZ);
        const float nn = tanh_f(accN1[rt][s][q] + bN1 + rg * (accN2[rt][s][q] + bN2));
        xh[row * 144 + 16 + hcol] = f2u((1.f - zg) * nn + zg * hp);
      }
    }
  }
}

// ---------------------------------------------------------------------------
// MFMA 2-layer tanh encoder. MODE 0 = En, MODE 1 = Ee.
// ---------------------------------------------------------------------------
template<int MODE>
__global__ __launch_bounds__(256, 2) void enc_mfma(
    ush* __restrict__ xh, ush* __restrict__ eh,
    const ush* __restrict__ WB1, const float* __restrict__ b1,
    const ush* __restrict__ WB2, const float* __restrict__ b2)
{
  __shared__ ush A1[64 * 32];
  __shared__ ush Z1[4 * 64 * 32];
  __shared__ ush B1s[128 * 32];
  __shared__ ush B2s[4 * 128 * 32];
  const int t = threadIdx.x, lane = t & 63, w = t >> 6;
  const int rowBase = blockIdx.x * 64;

  #pragma unroll
  for (int ii = 0; ii < 2; ++ii) { const int o = (t + ii * 256) * 8; *(s16x8*)&B1s[o] = *(const s16x8*)&WB1[o]; }
  #pragma unroll
  for (int ii = 0; ii < 8; ++ii) { const int o = (t + ii * 256) * 8; *(s16x8*)&B2s[o] = *(const s16x8*)&WB2[o]; }
  {
    const int gm = t >> 2, gb = t & 3, grow = rowBase + gm;
    s16x8 v;
    #pragma unroll
    for (int z = 0; z < 8; ++z) v[z] = 0;
    if (MODE == 0) {
      if (gb < 2) v = *(const s16x8*)(xh + grow * 144 + gb * 8);
    } else {
      const int n = grow >> 6, i = (grow >> 3) & 7, j = grow & 7;
      v = (gb < 2) ? *(const s16x8*)(xh + (n * 8 + i) * 144 + gb * 8)
                   : *(const s16x8*)(xh + (n * 8 + j) * 144 + (gb - 2) * 8);
    }
    *(s16x8*)&A1[swz_blk(gm, gb)] = v;
  }
  __syncthreads();

  s16x8 af[4];
  #pragma unroll
  for (int rt = 0; rt < 4; ++rt)
    af[rt] = *(const s16x8*)&A1[swz_blk(rt * 16 + (lane & 15), lane >> 4)];
  f32x4 acc1[4][2];
  #pragma unroll
  for (int rt = 0; rt < 4; ++rt)
    #pragma unroll
    for (int ct = 0; ct < 2; ++ct) {
      #pragma unroll
      for (int q = 0; q < 4; ++q) acc1[rt][ct][q] = 0.f;
    }
  #pragma unroll
  for (int ct = 0; ct < 2; ++ct) {
    const int n = w * 32 + ct * 16 + (lane & 15);
    const s16x8 bf = *(const s16x8*)&B1s[swz_blk(n, lane >> 4)];
    #pragma unroll
    for (int rt = 0; rt < 4; ++rt) acc1[rt][ct] = MFMA(af[rt], bf, acc1[rt][ct]);
  }
  #pragma unroll
  for (int ct = 0; ct < 2; ++ct) {
    const int col = w * 32 + ct * 16 + (lane & 15);
    const int ck2 = col >> 5, kk = col & 31;
    #pragma unroll
    for (int rt = 0; rt < 4; ++rt) {
      #pragma unroll
      for (int q = 0; q < 4; ++q) {
        const int m = rt * 16 + (lane >> 4) * 4 + q;
        Z1[ck2 * 2048 + swz_idx(m, kk)] = f2u(tanh_f(acc1[rt][ct][q] + b1[col]));
      }
    }
  }
  __syncthreads();

  f32x4 acc2[4][2];
  #pragma unroll
  for (int rt = 0; rt < 4; ++rt)
    #pragma unroll
    for (int ct = 0; ct < 2; ++ct) {
      #pragma unroll
      for (int q = 0; q < 4; ++q) acc2[rt][ct][q] = 0.f;
    }
  for (int ck2 = 0; ck2 < 4; ++ck2) {
    #pragma unroll
    for (int rt = 0; rt < 4; ++rt)
      af[rt] = *(const s16x8*)&Z1[ck2 * 2048 + swz_blk(rt * 16 + (lane & 15), lane >> 4)];
    #pragma unroll
    for (int ct = 0; ct < 2; ++ct) {
      const int n = w * 32 + ct * 16 + (lane & 15);
      const s16x8 bf = *(const s16x8*)&B2s[ck2 * 4096 + swz_blk(n, lane >> 4)];
      #pragma unroll
      for (int rt = 0; rt < 4; ++rt) acc2[rt][ct] = MFMA(af[rt], bf, acc2[rt][ct]);
    }
  }
  #pragma unroll
  for (int ct = 0; ct < 2; ++ct) {
    const int col = w * 32 + ct * 16 + (lane & 15);
    #pragma unroll
    for (int rt = 0; rt < 4; ++rt) {
      #pragma unroll
      for (int q = 0; q < 4; ++q) {
        const int row = rowBase + rt * 16 + (lane >> 4) * 4 + q;
        const float v = tanh_f(acc2[rt][ct][q] + b2[col]);
        if (MODE == 0) xh[row * 144 + 16 + col] = f2u(v);
        else           eh[row * 128 + col] = f2u(v);
      }
    }
  }
}

// ---------------------------------------------------------------------------
// readout path
// ---------------------------------------------------------------------------
__global__ __launch_bounds__(256) void sums2(const ush* __restrict__ xh, const ush* __restrict__ eh,
                                             float* __restrict__ hsum, float* __restrict__ esum) {
  const int idx = blockIdx.x * 256 + threadIdx.x;    // 4096*128
  const int n = idx >> 7, hh = idx & 127;
  float hs = 0.f, es = 0.f;
  #pragma unroll
  for (int i = 0; i < 8; ++i) hs += u2f(xh[(n * 8 + i) * 144 + 16 + hh]);
  #pragma unroll
  for (int i = 0; i < 7; ++i) es += u2f(eh[((n * 8 + i) * 8 + i + 1) * 128 + hh]);
  hsum[idx] = hs;
  esum[idx] = es;
}

__global__ __launch_bounds__(256) void prep_gruWT_G(const float* __restrict__ Wih, const float* __restrict__ Whh,
                                                    float* __restrict__ WT) {
  const int idx = blockIdx.x * 256 + threadIdx.x;    // 384*512
  if (idx >= 384 * 512) return;
  const int kc = idx >> 9, cg = (idx >> 2) & 127, gate = idx & 3;
  const int row = (gate == 0) ? cg : (gate == 1) ? cg + 128 : cg + 256;
  float v = 0.f;
  if (kc < 256) { if (gate != 3) v = Wih[row * 256 + kc]; }
  else          { if (gate != 2) v = Whh[row * 128 + (kc - 256)]; }
  WT[idx] = v;
}

__global__ __launch_bounds__(256) void prep_biasG(const float* __restrict__ bih, const float* __restrict__ bhh,
                                                  float* __restrict__ bias) {
  const int idx = blockIdx.x * 256 + threadIdx.x;
  if (idx >= 512) return;
  const int cg = idx >> 2, gate = idx & 3;
  float v;
  if (gate == 0)      v = bih[cg] + bhh[cg];
  else if (gate == 1) v = bih[cg + 128] + bhh[cg + 128];
  else if (gate == 2) v = bih[cg + 256];
  else                v = bhh[cg + 256];
  bias[idx] = v;
}

__global__ __launch_bounds__(256) void gru_global(
    const float* __restrict__ hsum, const float* __restrict__ esum,
    float* __restrict__ g, const float* __restrict__ WT, const float* __restrict__ bias)
{
  constexpr int KT = 384;
  __shared__ float4 ATl4[KT * 4];
  __shared__ float4 Bl4[16 * 128];
  float* ATl = (float*)ATl4;
  const int t = threadIdx.x;
  const int rowBase = blockIdx.x * 16;
  for (int idx = t; idx < KT * 16; idx += 256) {
    const int kc = idx >> 4, r = idx & 15, grow = rowBase + r;
    float v = 0.f;
    if (kc < 128)      v = hsum[grow * 128 + kc];
    else if (kc < 256) v = esum[grow * 128 + (kc - 128)];
    ATl[idx] = v;
  }
  const int c = t & 127, rh = t >> 7;
  float accR[8], accZ[8], accN1[8];
  #pragma unroll
  for (int rr = 0; rr < 8; ++rr) { accR[rr] = 0.f; accZ[rr] = 0.f; accN1[rr] = 0.f; }
  const float4* WT4 = (const float4*)WT;
  for (int ck = 0; ck < 16; ++ck) {
    __syncthreads();
    #pragma unroll
    for (int ii = 0; ii < 8; ++ii) { const int idx = t + ii * 256; Bl4[idx] = WT4[ck * 2048 + idx]; }
    __syncthreads();
    const int kb = ck * 16;
    #pragma unroll
    for (int kcl = 0; kcl < 16; ++kcl) {
      const float4 wv = Bl4[kcl * 128 + c];
      const float4 a0 = ATl4[(kb + kcl) * 4 + rh * 2];
      const float4 a1 = ATl4[(kb + kcl) * 4 + rh * 2 + 1];
      const float av[8] = {a0.x, a0.y, a0.z, a0.w, a1.x, a1.y, a1.z, a1.w};
      #pragma unroll
      for (int rr = 0; rr < 8; ++rr) {
        accR[rr]  += wv.x * av[rr];
        accZ[rr]  += wv.y * av[rr];
        accN1[rr] += wv.z * av[rr];
      }
    }
  }
  const float4 bb = ((const float4*)bias)[c];
  #pragma unroll
  for (int rr = 0; rr < 8; ++rr) {
    const int grow = rowBase + rh * 8 + rr;
    const float rg = sigmoid_f(accR[rr] + bb.x);
    const float zg = sigmoid_f(accZ[rr] + bb.y);
    const float nn = tanh_f(accN1[rr] + bb.z + rg * bb.w);
    g[grow * 128 + c] = (1.f - zg) * nn;
  }
}

__global__ __launch_bounds__(256) void out_kernel(
    const float* __restrict__ g, const float* __restrict__ OW,
    const float* __restrict__ Ob, float* __restrict__ out)
{
  const int n = blockIdx.x * 4 + (threadIdx.x >> 6);
  const int lane = threadIdx.x & 63;
  float p = g[n * 128 + lane] * OW[lane] + g[n * 128 + 64 + lane] * OW[64 + lane];
  #pragma unroll
  for (int off = 32; off > 0; off >>= 1) p += __shfl_down(p, off, 64);
  if (lane == 0) out[n] = sigmoid_f(p + Ob[0]);
}

// ---------------------------------------------------------------------------
template<class PT>
static void run_all(void* const* d_in, void* d_out, void* d_ws, hipStream_t stream)
{
  const float* towers = (const float*)d_in[0];
  const float* EnW1 = (const float*)d_in[1];
  const float* EnB1 = (const float*)d_in[2];
  const float* EnW2 = (const float*)d_in[3];
  const float* EnB2 = (const float*)d_in[4];
  const float* EeW1 = (const float*)d_in[5];
  const float* EeB1 = (const float*)d_in[6];
  const float* EeW2 = (const float*)d_in[7];
  const float* EeB2 = (const float*)d_in[8];
  const float* UWih = (const float*)d_in[9];
  const float* UWhh = (const float*)d_in[10];
  const float* UBih = (const float*)d_in[11];
  const float* UBhh = (const float*)d_in[12];
  const float* MWih = (const float*)d_in[13];
  const float* MWhh = (const float*)d_in[14];
  const float* MBih = (const float*)d_in[15];
  const float* MBhh = (const float*)d_in[16];
  const float* GWih = (const float*)d_in[17];
  const float* GWhh = (const float*)d_in[18];
  const float* GBih = (const float*)d_in[19];
  const float* GBhh = (const float*)d_in[20];
  const float* OW   = (const float*)d_in[21];
  const float* Ob   = (const float*)d_in[22];

  char* ws = (char*)d_ws;
  size_t off = 0;
  auto take = [&](size_t b) { void* p = ws + off; off = (off + b + 255) & ~(size_t)255; return p; };
  ush*   xh     = (ush*)take((size_t)32768 * 144 * 2);
  ush*   eh     = (ush*)take((size_t)262144 * 128 * 2);
  PT*    Pq     = (PT*)take((size_t)32768 * 768 * sizeof(PT));
  float* g      = (float*)take((size_t)4096 * 128 * 4);
  float* hsum   = (float*)take((size_t)4096 * 128 * 4);
  float* esum   = (float*)take((size_t)4096 * 128 * 4);
  ush*   WPQ    = (ush*)take((size_t)5 * 768 * 32 * 2);
  ush*   WTh    = (ush*)take((size_t)4 * 384 * 32 * 2);
  ush*   WTu    = (ush*)take((size_t)9 * 512 * 32 * 2);
  ush*   WBen1  = (ush*)take((size_t)128 * 32 * 2);
  ush*   WBen2  = (ush*)take((size_t)4 * 128 * 32 * 2);
  ush*   WBee1  = (ush*)take((size_t)128 * 32 * 2);
  ush*   WBee2  = (ush*)take((size_t)4 * 128 * 32 * 2);
  float* biasM  = (float*)take(512 * 4);
  float* biasU  = (float*)take(512 * 4);
  float* WT_G   = (float*)take((size_t)384 * 512 * 4);
  float* biasG  = (float*)take(512 * 4);

  // ---- weight/state prep ----
  prep_xh_t<<<2048, 256, 0, stream>>>(towers, xh);
  prep_WPQ<<<480, 256, 0, stream>>>(MWih, WPQ);
  prep_WTh<<<192, 256, 0, stream>>>(MWhh, WTh);
  prep_WTu<<<576, 256, 0, stream>>>(UWih, UWhh, WTu);
  prep_wb<<<16, 256, 0, stream>>>(EnW1, WBen1, 0, 4096);
  prep_wb<<<64, 256, 0, stream>>>(EnW2, WBen2, 2, 16384);
  prep_wb<<<16, 256, 0, stream>>>(EeW1, WBee1, 1, 4096);
  prep_wb<<<64, 256, 0, stream>>>(EeW2, WBee2, 2, 16384);
  prep_bias4<<<2, 256, 0, stream>>>(MBih, MBhh, biasM);
  prep_bias4<<<2, 256, 0, stream>>>(UBih, UBhh, biasU);
  prep_gruWT_G<<<768, 256, 0, stream>>>(GWih, GWhh, WT_G);
  prep_biasG<<<2, 256, 0, stream>>>(GBih, GBhh, biasG);

  // ---- encoders ----
  enc_mfma<0><<<512, 256, 0, stream>>>(xh, eh, WBen1, EnB1, WBen2, EnB2);
  enc_mfma<1><<<4096, 256, 0, stream>>>(xh, eh, WBee1, EeB1, WBee2, EeB2);

  // ---- k = 3 message-passing iterations ----
  for (int it = 0; it < 3; ++it) {
    pq_mfma<PT><<<dim3(512, 2), 256, 0, stream>>>(xh, WPQ, biasM, Pq);
    edge_mfma<PT><<<4096, 256, 0, stream>>>(eh, WTh, Pq, biasM);
    gru_node<<<512, 256, 0, stream>>>(xh, eh, WTu, biasU);
  }

  // ---- global readout ----
  sums2<<<2048, 256, 0, stream>>>(xh, eh, hsum, esum);
  gru_global<<<256, 256, 0, stream>>>(hsum, esum, g, WT_G, biasG);
  out_kernel<<<1024, 256, 0, stream>>>(g, OW, Ob, (float*)d_out);
}

extern "C" void kernel_launch(void* const* d_in, const int* in_sizes, int n_in,
                              void* d_out, int out_size, void* d_ws, size_t ws_size,
                              hipStream_t stream)
{
  (void)in_sizes; (void)n_in; (void)out_size;
  // fp32-Pq footprint ~185 MB; bf16-Pq fallback ~135 MB.
  if (ws_size >= 187000000ULL) run_all<float>(d_in, d_out, d_ws, stream);
  else                         run_all<ush>(d_in, d_out, d_ws, stream);
}

// Round 7
// 563.120 us; speedup vs baseline: 1.2495x; 1.2495x over previous
//
#include <hip/hip_runtime.h>
#include <hip/hip_bf16.h>

typedef __hip_bfloat16 bf16;
typedef unsigned short ush;
typedef short s16x8 __attribute__((ext_vector_type(8)));
typedef ush u16x4 __attribute__((ext_vector_type(4)));
typedef float f32x4 __attribute__((ext_vector_type(4)));

#define DEV __device__ __forceinline__

DEV float sigmoid_f(float x) { return 1.f / (1.f + __expf(-x)); }
DEV float tanh_f(float x) { return 1.f - 2.f / (__expf(2.f * x) + 1.f); }

DEV float u2f(ush u) { unsigned int v = ((unsigned int)u) << 16; float f; __builtin_memcpy(&f, &v, 4); return f; }
DEV ush f2u(float f) { bf16 h = __float2bfloat16(f); ush u; __builtin_memcpy(&u, &h, 2); return u; }

DEV f32x4 MFMA(s16x8 a, s16x8 b, f32x4 c) {
  return __builtin_amdgcn_mfma_f32_16x16x32_bf16(a, b, c, 0, 0, 0);
}

DEV s16x8 z8() {
  s16x8 v;
  for (int z = 0; z < 8; ++z) v[z] = 0;
  return v;
}

// swizzled element index within a [rows][32] bf16 chunk: 16B blocks XOR'd by (row>>1)&3
DEV int swz_idx(int row, int kk) { return row * 32 + (((kk >> 3) ^ ((row >> 1) & 3)) << 3) + (kk & 7); }
DEV int swz_blk(int row, int blk) { return row * 32 + ((blk ^ ((row >> 1) & 3)) << 3); }

// ---------------------------------------------------------------------------
// Constants: N=4096 graphs, K=8 nodes, n_in=14, H=128, k=3 iters. Inputs fp32.
// xh:  [32768][144] bf16 = [towers(14), pad(2), h(128)]
// eh:  [262144][128] bf16
// PqT: [4096][768][8] bf16 = per-graph P/Q transposed: [half*384+gate*128+c][node]
//      P = xh@Wa^T + biasM fold (gates r,z,n1), Q = xh@Wb^T.
// Edge GRU = h-phase GEMM (K=128, gates r,z,n2) + INDICATOR chunk (K=16):
//      A[row][128+i]=1, A[row][136+j]=1; B[c][k<8]=P[c][k], B[c][8..15]=Q[c][k-8]
//      -> accumulators emerge with P[i]+Q[j] (and biases) pre-added.
// ---------------------------------------------------------------------------

__global__ __launch_bounds__(256) void prep_all(
    const float* __restrict__ towers,
    const float* __restrict__ MWih, const float* __restrict__ MWhh,
    const float* __restrict__ UWih, const float* __restrict__ UWhh,
    const float* __restrict__ EnW1, const float* __restrict__ EnW2,
    const float* __restrict__ EeW1, const float* __restrict__ EeW2,
    const float* __restrict__ MBih, const float* __restrict__ MBhh,
    const float* __restrict__ UBih, const float* __restrict__ UBhh,
    const float* __restrict__ GWih, const float* __restrict__ GWhh,
    const float* __restrict__ GBih, const float* __restrict__ GBhh,
    ush* __restrict__ xh, ush* __restrict__ WPQ, ush* __restrict__ WTh,
    ush* __restrict__ WTu, ush* __restrict__ WBen1, ush* __restrict__ WBen2,
    ush* __restrict__ WBee1, ush* __restrict__ WBee2,
    float* __restrict__ biasM, float* __restrict__ biasU,
    float* __restrict__ WT_G, float* __restrict__ biasG, ush* __restrict__ bn2rep)
{
  const int b = blockIdx.x, t = threadIdx.x;
  if (b < 2048) {                       // xh towers part: 32768*16
    const int idx = b * 256 + t;
    const int row = idx >> 4, kk = idx & 15;
    xh[row * 144 + kk] = f2u(kk < 14 ? towers[row * 14 + kk] : 0.f);
  } else if (b < 2528) {                // WPQ: 5*768*32
    const int idx = (b - 2048) * 256 + t;
    const int ck = idx / 24576, rem = idx % 24576, n = rem >> 5, kk = rem & 31;
    const int k = ck * 32 + kk;
    const int half = (n >= 384);
    const int m = n - half * 384;
    const int g = m >> 7, c = m & 127;
    const int row = g * 128 + c;
    int col = -1;
    if (k < 14)                  col = k;
    else if (k >= 16 && k < 144) col = k - 2;
    if (half && col >= 0)        col += 142;
    WPQ[idx] = f2u((col >= 0) ? MWih[row * 284 + col] : 0.f);
  } else if (b < 2720) {                // WTh: 4*384*32
    const int idx = (b - 2528) * 256 + t;
    const int ck = idx / 12288, rem = idx % 12288, n = rem >> 5, kk = rem & 31;
    const int g = n >> 7, c = n & 127;
    WTh[idx] = f2u(MWhh[(g * 128 + c) * 128 + ck * 32 + kk]);
  } else if (b < 3296) {                // WTu: 9*512*32 swizzled
    const int idx = (b - 2720) * 256 + t;
    const int ck = idx >> 14, n = (idx >> 5) & 511, kk = idx & 31;
    const int k = ck * 32 + kk, gate = n >> 7, c = n & 127;
    float w = 0.f;
    const int row = (gate == 0) ? c : (gate == 1) ? 128 + c : 256 + c;
    if (k < 160) {
      int col = -1;
      if (k < 16)        { if (k < 14) col = k; }
      else if (k < 144)  col = 14 + (k - 16);
      if (gate != 3 && col >= 0) w = UWih[row * 142 + col];
    } else {
      if (gate != 2) w = UWhh[row * 128 + (k - 160)];
    }
    WTu[ck * 16384 + swz_idx(n, kk)] = f2u(w);
  } else if (b < 3312) {                // WBen1: 128x14 pad32
    const int idx = (b - 3296) * 256 + t;
    const int n = (idx >> 5) & 127, kk = idx & 31;
    WBen1[swz_idx(n, kk)] = f2u(kk < 14 ? EnW1[n * 14 + kk] : 0.f);
  } else if (b < 3376) {                // WBen2: 128x128
    const int idx = (b - 3312) * 256 + t;
    const int ck = idx >> 12, n = (idx >> 5) & 127, kk = idx & 31;
    WBen2[ck * 4096 + swz_idx(n, kk)] = f2u(EnW2[n * 128 + ck * 32 + kk]);
  } else if (b < 3392) {                // WBee1: 128x28 pair
    const int idx = (b - 3376) * 256 + t;
    const int n = (idx >> 5) & 127, kk = idx & 31;
    int col = (kk < 16) ? (kk < 14 ? kk : -1) : (kk < 30 ? 14 + (kk - 16) : -1);
    WBee1[swz_idx(n, kk)] = f2u(col >= 0 ? EeW1[n * 28 + col] : 0.f);
  } else if (b < 3456) {                // WBee2: 128x128
    const int idx = (b - 3392) * 256 + t;
    const int ck = idx >> 12, n = (idx >> 5) & 127, kk = idx & 31;
    WBee2[ck * 4096 + swz_idx(n, kk)] = f2u(EeW2[n * 128 + ck * 32 + kk]);
  } else if (b < 3458) {                // biasM [4 gates][128]
    const int idx = (b - 3456) * 256 + t;
    const int g = idx >> 7, c = idx & 127;
    float v;
    if (g == 0)      v = MBih[c] + MBhh[c];
    else if (g == 1) v = MBih[128 + c] + MBhh[128 + c];
    else if (g == 2) v = MBih[256 + c];
    else             v = MBhh[256 + c];
    biasM[idx] = v;
  } else if (b < 3460) {                // biasU
    const int idx = (b - 3458) * 256 + t;
    const int g = idx >> 7, c = idx & 127;
    float v;
    if (g == 0)      v = UBih[c] + UBhh[c];
    else if (g == 1) v = UBih[128 + c] + UBhh[128 + c];
    else if (g == 2) v = UBih[256 + c];
    else             v = UBhh[256 + c];
    biasU[idx] = v;
  } else if (b < 4228) {                // WT_G interleaved fp32: 384*512
    const int idx = (b - 3460) * 256 + t;
    const int kc = idx >> 9, cg = (idx >> 2) & 127, gate = idx & 3;
    const int row = (gate == 0) ? cg : (gate == 1) ? cg + 128 : cg + 256;
    float v = 0.f;
    if (kc < 256) { if (gate != 3) v = GWih[row * 256 + kc]; }
    else          { if (gate != 2) v = GWhh[row * 128 + (kc - 256)]; }
    WT_G[idx] = v;
  } else if (b < 4230) {                // biasG
    const int idx = (b - 4228) * 256 + t;
    const int cg = idx >> 2, gate = idx & 3;
    float v;
    if (gate == 0)      v = GBih[cg] + GBhh[cg];
    else if (gate == 1) v = GBih[cg + 128] + GBhh[cg + 128];
    else if (gate == 2) v = GBih[cg + 256];
    else                v = GBhh[cg + 256];
    biasG[idx] = v;
  } else {                              // bn2rep: [128][8] = bhh_n replicated
    const int idx = (b - 4230) * 256 + t;   // 1024
    bn2rep[idx] = f2u(MBhh[256 + (idx >> 3)]);
  }
}

// ---------------------------------------------------------------------------
// PQ GEMM: per-graph transposed store PqT[g][768][8] bf16.
// Block = 64 rows x 384 cols (blockIdx.y = P/Q half); wave = 96 cols.
// ---------------------------------------------------------------------------
__global__ __launch_bounds__(256, 2) void pq_mfma(
    const ush* __restrict__ xh, const ush* __restrict__ WPQ,
    const float* __restrict__ biasM, ush* __restrict__ PqT)
{
  __shared__ ush As[5 * 64 * 32];
  const int t = threadIdx.x, lane = t & 63, w = t >> 6;
  const int rowBase = blockIdx.x * 64, half = blockIdx.y;
  const int gm = t >> 2, gb = t & 3, grow = rowBase + gm;

  #pragma unroll
  for (int ck = 0; ck < 5; ++ck) {
    const int k0 = ck * 32 + gb * 8;
    s16x8 v = z8();
    if (k0 < 144) v = *(const s16x8*)(xh + grow * 144 + k0);
    *(s16x8*)&As[ck * 2048 + swz_blk(gm, gb)] = v;
  }
  __syncthreads();

  f32x4 acc[6][4];
  #pragma unroll
  for (int tl = 0; tl < 6; ++tl)
    #pragma unroll
    for (int rt = 0; rt < 4; ++rt) {
      #pragma unroll
      for (int q = 0; q < 4; ++q) acc[tl][rt][q] = 0.f;
    }

  for (int ck = 0; ck < 5; ++ck) {
    s16x8 af[4];
    #pragma unroll
    for (int rt = 0; rt < 4; ++rt)
      af[rt] = *(const s16x8*)&As[ck * 2048 + swz_blk(rt * 16 + (lane & 15), lane >> 4)];
    #pragma unroll
    for (int tl = 0; tl < 6; ++tl) {
      const int n = w * 96 + tl * 16 + (lane & 15);
      const s16x8 bf = *(const s16x8*)&WPQ[(ck * 768 + half * 384 + n) * 32 + (lane >> 4) * 8];
      #pragma unroll
      for (int rt = 0; rt < 4; ++rt) acc[tl][rt] = MFMA(af[rt], bf, acc[tl][rt]);
    }
  }

  #pragma unroll
  for (int tl = 0; tl < 6; ++tl) {
    const int col = w * 96 + tl * 16 + (lane & 15);      // 0..383 within half
    const float bv = half ? 0.f : biasM[col];
    #pragma unroll
    for (int rt = 0; rt < 4; ++rt) {
      const int row0 = rowBase + rt * 16 + (lane >> 4) * 4;   // 4-aligned
      const int g = row0 >> 3, n0 = row0 & 7;                 // n0 in {0,4}
      u16x4 wv;
      #pragma unroll
      for (int q = 0; q < 4; ++q) wv[q] = f2u(acc[tl][rt][q] + bv);
      *(u16x4*)&PqT[(g * 768 + half * 384 + col) * 8 + n0] = wv;
    }
  }
}

// ---------------------------------------------------------------------------
// Edge GRU: block = 1 graph = 64 edge rows. 4 eh chunks (gates r,z,n2) +
// indicator chunk (all 4 gates; B from PqT / bn2rep). Epilogue: pure math.
// ---------------------------------------------------------------------------
__global__ __launch_bounds__(256, 2) void edge_mfma(
    ush* __restrict__ eh, const ush* __restrict__ WTh,
    const ush* __restrict__ PqT, const ush* __restrict__ bn2rep)
{
  __shared__ ush As[5 * 64 * 32];     // chunks 0-3: e_h 64x128; chunk 4: indicator
  const int t = threadIdx.x, lane = t & 63, w = t >> 6;
  const int g = blockIdx.x, rowBase = g * 64;

  {
    const int gm = t >> 2, gb = t & 3;
    #pragma unroll
    for (int ck = 0; ck < 4; ++ck) {
      const s16x8 v = *(const s16x8*)(eh + (rowBase + gm) * 128 + ck * 32 + gb * 8);
      *(s16x8*)&As[ck * 2048 + swz_blk(gm, gb)] = v;
    }
    s16x8 v = z8();
    if (gb == 0)      v[gm >> 3] = (short)0x3F80;   // one-hot i
    else if (gb == 1) v[gm & 7]  = (short)0x3F80;   // one-hot j
    *(s16x8*)&As[4 * 2048 + swz_blk(gm, gb)] = v;
  }
  __syncthreads();

  f32x4 accR[4][2], accZ[4][2], accN1[4][2], accN2[4][2];
  #pragma unroll
  for (int rt = 0; rt < 4; ++rt)
    #pragma unroll
    for (int s = 0; s < 2; ++s) {
      #pragma unroll
      for (int q = 0; q < 4; ++q) { accR[rt][s][q] = 0.f; accZ[rt][s][q] = 0.f; accN1[rt][s][q] = 0.f; accN2[rt][s][q] = 0.f; }
    }

  #pragma unroll
  for (int ck = 0; ck < 4; ++ck) {
    s16x8 af[4];
    #pragma unroll
    for (int rt = 0; rt < 4; ++rt)
      af[rt] = *(const s16x8*)&As[ck * 2048 + swz_blk(rt * 16 + (lane & 15), lane >> 4)];
    #pragma unroll
    for (int s = 0; s < 2; ++s) {
      const int nb = w * 32 + s * 16 + (lane & 15);
      const int ko = (lane >> 4) * 8;
      const s16x8 bR = *(const s16x8*)&WTh[(ck * 384 + nb) * 32 + ko];
      const s16x8 bZ = *(const s16x8*)&WTh[(ck * 384 + 128 + nb) * 32 + ko];
      const s16x8 bN = *(const s16x8*)&WTh[(ck * 384 + 256 + nb) * 32 + ko];
      #pragma unroll
      for (int rt = 0; rt < 4; ++rt) {
        accR[rt][s]  = MFMA(af[rt], bR, accR[rt][s]);
        accZ[rt][s]  = MFMA(af[rt], bZ, accZ[rt][s]);
        accN2[rt][s] = MFMA(af[rt], bN, accN2[rt][s]);
      }
    }
  }
  // indicator chunk: B from per-graph PqT (k<8 -> P, k 8..15 -> Q, else 0)
  {
    s16x8 af5[4];
    #pragma unroll
    for (int rt = 0; rt < 4; ++rt)
      af5[rt] = *(const s16x8*)&As[4 * 2048 + swz_blk(rt * 16 + (lane & 15), lane >> 4)];
    const int ksel = lane >> 4;
    #pragma unroll
    for (int s = 0; s < 2; ++s) {
      const int c = w * 32 + s * 16 + (lane & 15);
      s16x8 bR = z8(), bZ = z8(), bN1 = z8(), bN2 = z8();
      if (ksel < 2) {
        const ush* base = PqT + (g * 768 + ksel * 384) * 8;
        bR  = *(const s16x8*)&base[(c) * 8];
        bZ  = *(const s16x8*)&base[(128 + c) * 8];
        bN1 = *(const s16x8*)&base[(256 + c) * 8];
      }
      if (ksel == 0) bN2 = *(const s16x8*)&bn2rep[c * 8];
      #pragma unroll
      for (int rt = 0; rt < 4; ++rt) {
        accR[rt][s]  = MFMA(af5[rt], bR,  accR[rt][s]);
        accZ[rt][s]  = MFMA(af5[rt], bZ,  accZ[rt][s]);
        accN1[rt][s] = MFMA(af5[rt], bN1, accN1[rt][s]);
        accN2[rt][s] = MFMA(af5[rt], bN2, accN2[rt][s]);
      }
    }
  }

  // epilogue: everything already in accumulators
  #pragma unroll
  for (int s = 0; s < 2; ++s) {
    const int hcol = w * 32 + s * 16 + (lane & 15);
    #pragma unroll
    for (int rt = 0; rt < 4; ++rt) {
      #pragma unroll
      for (int q = 0; q < 4; ++q) {
        const int row = rt * 16 + (lane >> 4) * 4 + q;    // 0..63 local
        const float rg = sigmoid_f(accR[rt][s][q]);
        const float zg = sigmoid_f(accZ[rt][s][q]);
        const float nn = tanh_f(accN1[rt][s][q] + rg * accN2[rt][s][q]);
        const float hp = u2f(As[(hcol >> 5) * 2048 + swz_idx(row, hcol & 31)]);
        eh[(rowBase + row) * 128 + hcol] = f2u((1.f - zg) * nn + zg * hp);
      }
    }
  }
}

// ---------------------------------------------------------------------------
// Node GRU (MFMA): 64 rows x 512 gate-cols per block.
// ---------------------------------------------------------------------------
__global__ __launch_bounds__(256, 2) void gru_node(
    ush* __restrict__ xh, const ush* __restrict__ eh,
    const ush* __restrict__ WT, const float* __restrict__ bias)
{
  constexpr int NCH = 9, XCH = 5;
  __shared__ ush As[64 * 32];
  __shared__ ush Bs[512 * 32];
  const int t = threadIdx.x, lane = t & 63, w = t >> 6;
  const int rowBase = blockIdx.x * 64;
  const int gm = t >> 2, gb = t & 3, grow = rowBase + gm;

  f32x4 accR[4][2], accZ[4][2], accN1[4][2], accN2[4][2];
  #pragma unroll
  for (int rt = 0; rt < 4; ++rt)
    #pragma unroll
    for (int s = 0; s < 2; ++s) {
      #pragma unroll
      for (int q = 0; q < 4; ++q) { accR[rt][s][q] = 0.f; accZ[rt][s][q] = 0.f; accN1[rt][s][q] = 0.f; accN2[rt][s][q] = 0.f; }
    }

  for (int ck = 0; ck < NCH; ++ck) {
    const ush* wsrc = WT + ck * 16384;
    #pragma unroll
    for (int ii = 0; ii < 8; ++ii) {
      const int o = (t + ii * 256) * 8;
      *(s16x8*)&Bs[o] = *(const s16x8*)&wsrc[o];
    }
    {
      const int k0 = ck * 32 + gb * 8;
      s16x8 v = z8();
      if (k0 < 16)       v = *(const s16x8*)(xh + grow * 144 + k0);
      else if (k0 < 144) {
        const int i = grow & 7;
        if (i < 7) v = *(const s16x8*)(eh + (grow * 8 + i + 1) * 128 + (k0 - 16));
      } else if (k0 >= 160) {
        v = *(const s16x8*)(xh + grow * 144 + 16 + (k0 - 160));
      }
      *(s16x8*)&As[swz_blk(gm, gb)] = v;
    }
    __syncthreads();

    s16x8 af[4];
    #pragma unroll
    for (int rt = 0; rt < 4; ++rt)
      af[rt] = *(const s16x8*)&As[swz_blk(rt * 16 + (lane & 15), lane >> 4)];
    if (ck < XCH) {
      #pragma unroll
      for (int s = 0; s < 2; ++s) {
        const int nb = w * 32 + s * 16 + (lane & 15);
        const s16x8 bR = *(const s16x8*)&Bs[swz_blk(0 * 128 + nb, lane >> 4)];
        const s16x8 bZ = *(const s16x8*)&Bs[swz_blk(1 * 128 + nb, lane >> 4)];
        const s16x8 bN = *(const s16x8*)&Bs[swz_blk(2 * 128 + nb, lane >> 4)];
        #pragma unroll
        for (int rt = 0; rt < 4; ++rt) {
          accR[rt][s]  = MFMA(af[rt], bR, accR[rt][s]);
          accZ[rt][s]  = MFMA(af[rt], bZ, accZ[rt][s]);
          accN1[rt][s] = MFMA(af[rt], bN, accN1[rt][s]);
        }
      }
    } else {
      #pragma unroll
      for (int s = 0; s < 2; ++s) {
        const int nb = w * 32 + s * 16 + (lane & 15);
        const s16x8 bR = *(const s16x8*)&Bs[swz_blk(0 * 128 + nb, lane >> 4)];
        const s16x8 bZ = *(const s16x8*)&Bs[swz_blk(1 * 128 + nb, lane >> 4)];
        const s16x8 bN = *(const s16x8*)&Bs[swz_blk(3 * 128 + nb, lane >> 4)];
        #pragma unroll
        for (int rt = 0; rt < 4; ++rt) {
          accR[rt][s]  = MFMA(af[rt], bR, accR[rt][s]);
          accZ[rt][s]  = MFMA(af[rt], bZ, accZ[rt][s]);
          accN2[rt][s] = MFMA(af[rt], bN, accN2[rt][s]);
        }
      }
    }
    __syncthreads();
  }

  #pragma unroll
  for (int s = 0; s < 2; ++s) {
    const int hcol = w * 32 + s * 16 + (lane & 15);
    const float bR = bias[hcol], bZ = bias[128 + hcol], bN1 = bias[256 + hcol], bN2 = bias[384 + hcol];
    #pragma unroll
    for (int rt = 0; rt < 4; ++rt) {
      #pragma unroll
      for (int q = 0; q < 4; ++q) {
        const int row = rowBase + rt * 16 + (lane >> 4) * 4 + q;
        const float hp = u2f(xh[row * 144 + 16 + hcol]);
        const float rg = sigmoid_f(accR[rt][s][q] + bR);
        const float zg = sigmoid_f(accZ[rt][s][q] + bZ);
        const float nn = tanh_f(accN1[rt][s][q] + bN1 + rg * (accN2[rt][s][q] + bN2));
        xh[row * 144 + 16 + hcol] = f2u((1.f - zg) * nn + zg * hp);
      }
    }
  }
}

// ---------------------------------------------------------------------------
// MFMA 2-layer tanh encoder. MODE 0 = En, MODE 1 = Ee.
// ---------------------------------------------------------------------------
template<int MODE>
__global__ __launch_bounds__(256, 2) void enc_mfma(
    ush* __restrict__ xh, ush* __restrict__ eh,
    const ush* __restrict__ WB1, const float* __restrict__ b1,
    const ush* __restrict__ WB2, const float* __restrict__ b2)
{
  __shared__ ush A1[64 * 32];
  __shared__ ush Z1[4 * 64 * 32];
  __shared__ ush B1s[128 * 32];
  __shared__ ush B2s[4 * 128 * 32];
  const int t = threadIdx.x, lane = t & 63, w = t >> 6;
  const int rowBase = blockIdx.x * 64;

  #pragma unroll
  for (int ii = 0; ii < 2; ++ii) { const int o = (t + ii * 256) * 8; *(s16x8*)&B1s[o] = *(const s16x8*)&WB1[o]; }
  #pragma unroll
  for (int ii = 0; ii < 8; ++ii) { const int o = (t + ii * 256) * 8; *(s16x8*)&B2s[o] = *(const s16x8*)&WB2[o]; }
  {
    const int gm = t >> 2, gb = t & 3, grow = rowBase + gm;
    s16x8 v = z8();
    if (MODE == 0) {
      if (gb < 2) v = *(const s16x8*)(xh + grow * 144 + gb * 8);
    } else {
      const int n = grow >> 6, i = (grow >> 3) & 7, j = grow & 7;
      v = (gb < 2) ? *(const s16x8*)(xh + (n * 8 + i) * 144 + gb * 8)
                   : *(const s16x8*)(xh + (n * 8 + j) * 144 + (gb - 2) * 8);
    }
    *(s16x8*)&A1[swz_blk(gm, gb)] = v;
  }
  __syncthreads();

  s16x8 af[4];
  #pragma unroll
  for (int rt = 0; rt < 4; ++rt)
    af[rt] = *(const s16x8*)&A1[swz_blk(rt * 16 + (lane & 15), lane >> 4)];
  f32x4 acc1[4][2];
  #pragma unroll
  for (int rt = 0; rt < 4; ++rt)
    #pragma unroll
    for (int ct = 0; ct < 2; ++ct) {
      #pragma unroll
      for (int q = 0; q < 4; ++q) acc1[rt][ct][q] = 0.f;
    }
  #pragma unroll
  for (int ct = 0; ct < 2; ++ct) {
    const int n = w * 32 + ct * 16 + (lane & 15);
    const s16x8 bf = *(const s16x8*)&B1s[swz_blk(n, lane >> 4)];
    #pragma unroll
    for (int rt = 0; rt < 4; ++rt) acc1[rt][ct] = MFMA(af[rt], bf, acc1[rt][ct]);
  }
  #pragma unroll
  for (int ct = 0; ct < 2; ++ct) {
    const int col = w * 32 + ct * 16 + (lane & 15);
    const int ck2 = col >> 5, kk = col & 31;
    #pragma unroll
    for (int rt = 0; rt < 4; ++rt) {
      #pragma unroll
      for (int q = 0; q < 4; ++q) {
        const int m = rt * 16 + (lane >> 4) * 4 + q;
        Z1[ck2 * 2048 + swz_idx(m, kk)] = f2u(tanh_f(acc1[rt][ct][q] + b1[col]));
      }
    }
  }
  __syncthreads();

  f32x4 acc2[4][2];
  #pragma unroll
  for (int rt = 0; rt < 4; ++rt)
    #pragma unroll
    for (int ct = 0; ct < 2; ++ct) {
      #pragma unroll
      for (int q = 0; q < 4; ++q) acc2[rt][ct][q] = 0.f;
    }
  for (int ck2 = 0; ck2 < 4; ++ck2) {
    #pragma unroll
    for (int rt = 0; rt < 4; ++rt)
      af[rt] = *(const s16x8*)&Z1[ck2 * 2048 + swz_blk(rt * 16 + (lane & 15), lane >> 4)];
    #pragma unroll
    for (int ct = 0; ct < 2; ++ct) {
      const int n = w * 32 + ct * 16 + (lane & 15);
      const s16x8 bf = *(const s16x8*)&B2s[ck2 * 4096 + swz_blk(n, lane >> 4)];
      #pragma unroll
      for (int rt = 0; rt < 4; ++rt) acc2[rt][ct] = MFMA(af[rt], bf, acc2[rt][ct]);
    }
  }
  #pragma unroll
  for (int ct = 0; ct < 2; ++ct) {
    const int col = w * 32 + ct * 16 + (lane & 15);
    #pragma unroll
    for (int rt = 0; rt < 4; ++rt) {
      #pragma unroll
      for (int q = 0; q < 4; ++q) {
        const int row = rowBase + rt * 16 + (lane >> 4) * 4 + q;
        const float v = tanh_f(acc2[rt][ct][q] + b2[col]);
        if (MODE == 0) xh[row * 144 + 16 + col] = f2u(v);
        else           eh[row * 128 + col] = f2u(v);
      }
    }
  }
}

// ---------------------------------------------------------------------------
// readout path
// ---------------------------------------------------------------------------
__global__ __launch_bounds__(256) void sums2(const ush* __restrict__ xh, const ush* __restrict__ eh,
                                             float* __restrict__ hsum, float* __restrict__ esum) {
  const int idx = blockIdx.x * 256 + threadIdx.x;    // 4096*128
  const int n = idx >> 7, hh = idx & 127;
  float hs = 0.f, es = 0.f;
  #pragma unroll
  for (int i = 0; i < 8; ++i) hs += u2f(xh[(n * 8 + i) * 144 + 16 + hh]);
  #pragma unroll
  for (int i = 0; i < 7; ++i) es += u2f(eh[((n * 8 + i) * 8 + i + 1) * 128 + hh]);
  hsum[idx] = hs;
  esum[idx] = es;
}

// global GRU (h_prev = 0) fused with output head: 16 graphs per block.
__global__ __launch_bounds__(256) void gru_global_out(
    const float* __restrict__ hsum, const float* __restrict__ esum,
    const float* __restrict__ WT, const float* __restrict__ bias,
    const float* __restrict__ OW, const float* __restrict__ Ob,
    float* __restrict__ out)
{
  constexpr int KT = 384;
  __shared__ float4 ATl4[KT * 4];
  __shared__ float4 Bl4[16 * 128];
  __shared__ float gmat[16 * 128];
  __shared__ float red[16 * 4];
  float* ATl = (float*)ATl4;
  const int t = threadIdx.x;
  const int rowBase = blockIdx.x * 16;
  for (int idx = t; idx < KT * 16; idx += 256) {
    const int kc = idx >> 4, r = idx & 15, grow = rowBase + r;
    float v = 0.f;
    if (kc < 128)      v = hsum[grow * 128 + kc];
    else if (kc < 256) v = esum[grow * 128 + (kc - 128)];
    ATl[idx] = v;
  }
  const int c = t & 127, rh = t >> 7;
  float accR[8], accZ[8], accN1[8];
  #pragma unroll
  for (int rr = 0; rr < 8; ++rr) { accR[rr] = 0.f; accZ[rr] = 0.f; accN1[rr] = 0.f; }
  const float4* WT4 = (const float4*)WT;
  for (int ck = 0; ck < 16; ++ck) {
    __syncthreads();
    #pragma unroll
    for (int ii = 0; ii < 8; ++ii) { const int idx = t + ii * 256; Bl4[idx] = WT4[ck * 2048 + idx]; }
    __syncthreads();
    const int kb = ck * 16;
    #pragma unroll
    for (int kcl = 0; kcl < 16; ++kcl) {
      const float4 wv = Bl4[kcl * 128 + c];
      const float4 a0 = ATl4[(kb + kcl) * 4 + rh * 2];
      const float4 a1 = ATl4[(kb + kcl) * 4 + rh * 2 + 1];
      const float av[8] = {a0.x, a0.y, a0.z, a0.w, a1.x, a1.y, a1.z, a1.w};
      #pragma unroll
      for (int rr = 0; rr < 8; ++rr) {
        accR[rr]  += wv.x * av[rr];
        accZ[rr]  += wv.y * av[rr];
        accN1[rr] += wv.z * av[rr];
      }
    }
  }
  const float4 bb = ((const float4*)bias)[c];
  const float ow = OW[c];
  #pragma unroll
  for (int rr = 0; rr < 8; ++rr) {
    const float rg = sigmoid_f(accR[rr] + bb.x);
    const float zg = sigmoid_f(accZ[rr] + bb.y);
    const float nn = tanh_f(accN1[rr] + bb.z + rg * bb.w);
    gmat[(rh * 8 + rr) * 128 + c] = (1.f - zg) * nn * ow;
  }
  __syncthreads();
  if (t < 64) {
    const int r = t >> 2, part = t & 3;
    float s = 0.f;
    #pragma unroll
    for (int cc = 0; cc < 32; ++cc) s += gmat[r * 128 + part * 32 + cc];
    red[r * 4 + part] = s;
  }
  __syncthreads();
  if (t < 16) {
    const float s = red[t * 4] + red[t * 4 + 1] + red[t * 4 + 2] + red[t * 4 + 3];
    out[rowBase + t] = sigmoid_f(s + Ob[0]);
  }
}

// ---------------------------------------------------------------------------
extern "C" void kernel_launch(void* const* d_in, const int* in_sizes, int n_in,
                              void* d_out, int out_size, void* d_ws, size_t ws_size,
                              hipStream_t stream)
{
  (void)in_sizes; (void)n_in; (void)out_size; (void)ws_size;
  const float* towers = (const float*)d_in[0];
  const float* EnW1 = (const float*)d_in[1];
  const float* EnB1 = (const float*)d_in[2];
  const float* EnW2 = (const float*)d_in[3];
  const float* EnB2 = (const float*)d_in[4];
  const float* EeW1 = (const float*)d_in[5];
  const float* EeB1 = (const float*)d_in[6];
  const float* EeW2 = (const float*)d_in[7];
  const float* EeB2 = (const float*)d_in[8];
  const float* UWih = (const float*)d_in[9];
  const float* UWhh = (const float*)d_in[10];
  const float* UBih = (const float*)d_in[11];
  const float* UBhh = (const float*)d_in[12];
  const float* MWih = (const float*)d_in[13];
  const float* MWhh = (const float*)d_in[14];
  const float* MBih = (const float*)d_in[15];
  const float* MBhh = (const float*)d_in[16];
  const float* GWih = (const float*)d_in[17];
  const float* GWhh = (const float*)d_in[18];
  const float* GBih = (const float*)d_in[19];
  const float* GBhh = (const float*)d_in[20];
  const float* OW   = (const float*)d_in[21];
  const float* Ob   = (const float*)d_in[22];

  char* ws = (char*)d_ws;
  size_t off = 0;
  auto take = [&](size_t b) { void* p = ws + off; off = (off + b + 255) & ~(size_t)255; return p; };
  ush*   xh     = (ush*)take((size_t)32768 * 144 * 2);
  ush*   eh     = (ush*)take((size_t)262144 * 128 * 2);
  ush*   PqT    = (ush*)take((size_t)4096 * 768 * 8 * 2);
  float* hsum   = (float*)take((size_t)4096 * 128 * 4);
  float* esum   = (float*)take((size_t)4096 * 128 * 4);
  ush*   WPQ    = (ush*)take((size_t)5 * 768 * 32 * 2);
  ush*   WTh    = (ush*)take((size_t)4 * 384 * 32 * 2);
  ush*   WTu    = (ush*)take((size_t)9 * 512 * 32 * 2);
  ush*   WBen1  = (ush*)take((size_t)128 * 32 * 2);
  ush*   WBen2  = (ush*)take((size_t)4 * 128 * 32 * 2);
  ush*   WBee1  = (ush*)take((size_t)128 * 32 * 2);
  ush*   WBee2  = (ush*)take((size_t)4 * 128 * 32 * 2);
  float* biasM  = (float*)take(512 * 4);
  float* biasU  = (float*)take(512 * 4);
  float* WT_G   = (float*)take((size_t)384 * 512 * 4);
  float* biasG  = (float*)take(512 * 4);
  ush*   bn2rep = (ush*)take(128 * 8 * 2);

  // ---- all weight/state prep in one launch ----
  prep_all<<<4234, 256, 0, stream>>>(
      towers, MWih, MWhh, UWih, UWhh, EnW1, EnW2, EeW1, EeW2,
      MBih, MBhh, UBih, UBhh, GWih, GWhh, GBih, GBhh,
      xh, WPQ, WTh, WTu, WBen1, WBen2, WBee1, WBee2,
      biasM, biasU, WT_G, biasG, bn2rep);

  // ---- encoders ----
  enc_mfma<0><<<512, 256, 0, stream>>>(xh, eh, WBen1, EnB1, WBen2, EnB2);
  enc_mfma<1><<<4096, 256, 0, stream>>>(xh, eh, WBee1, EeB1, WBee2, EeB2);

  // ---- k = 3 message-passing iterations ----
  for (int it = 0; it < 3; ++it) {
    pq_mfma<<<dim3(512, 2), 256, 0, stream>>>(xh, WPQ, biasM, PqT);
    edge_mfma<<<4096, 256, 0, stream>>>(eh, WTh, PqT, bn2rep);
    gru_node<<<512, 256, 0, stream>>>(xh, eh, WTu, biasU);
  }

  // ---- global readout ----
  sums2<<<2048, 256, 0, stream>>>(xh, eh, hsum, esum);
  gru_global_out<<<256, 256, 0, stream>>>(hsum, esum, WT_G, biasG, OW, Ob, (float*)d_out);
}

// Round 8
// 494.016 us; speedup vs baseline: 1.4243x; 1.1399x over previous
//
#include <hip/hip_runtime.h>
#include <hip/hip_bf16.h>

typedef __hip_bfloat16 bf16;
typedef unsigned short ush;
typedef short s16x8 __attribute__((ext_vector_type(8)));
typedef ush u16x4 __attribute__((ext_vector_type(4)));
typedef float f32x4 __attribute__((ext_vector_type(4)));

#define DEV __device__ __forceinline__

// v_rcp_f32 (~1 ULP) instead of exact-division sequence (no -ffast-math in harness)
DEV float rcp_f(float x) { return __builtin_amdgcn_rcpf(x); }
DEV float sigmoid_f(float x) { return rcp_f(1.f + __expf(-x)); }
DEV float tanh_f(float x) { return 1.f - 2.f * rcp_f(__expf(2.f * x) + 1.f); }

DEV float u2f(ush u) { unsigned int v = ((unsigned int)u) << 16; float f; __builtin_memcpy(&f, &v, 4); return f; }
DEV ush f2u(float f) { bf16 h = __float2bfloat16(f); ush u; __builtin_memcpy(&u, &h, 2); return u; }

DEV f32x4 MFMA(s16x8 a, s16x8 b, f32x4 c) {
  return __builtin_amdgcn_mfma_f32_16x16x32_bf16(a, b, c, 0, 0, 0);
}

DEV s16x8 z8() {
  s16x8 v;
  for (int z = 0; z < 8; ++z) v[z] = 0;
  return v;
}

// swizzled element index within a [rows][32] bf16 chunk: 16B blocks XOR'd by (row>>1)&3
DEV int swz_idx(int row, int kk) { return row * 32 + (((kk >> 3) ^ ((row >> 1) & 3)) << 3) + (kk & 7); }
DEV int swz_blk(int row, int blk) { return row * 32 + ((blk ^ ((row >> 1) & 3)) << 3); }

// ---------------------------------------------------------------------------
// Constants: N=4096 graphs, K=8 nodes, n_in=14, H=128, k=3 iters. Inputs fp32.
// xh:  [32768][144] bf16 = [towers(14), pad(2), h(128)]
// eh:  [262144][128] bf16
// PqT: [4096][768][8] bf16 = per-graph P/Q transposed: [half*384+gate*128+c][node]
// Edge GRU (TRANSPOSED-C form): D[m=gatecol][n=edgerow] = WTh·eh^T + indicator:
//   A = WTh (h-phase, gates r,z,n2) over K=128, plus indicator K-chunk where
//   A = PqT/bn2rep (k<8 = P/node, k 8..15 = Q/node) and B[k][edgerow] is the
//   in-register one-hot of (i, j). Lane then holds 4 consecutive hcols ->
//   8B hp reads + 8B packed stores in the epilogue.
// ---------------------------------------------------------------------------

__global__ __launch_bounds__(256) void prep_all(
    const float* __restrict__ towers,
    const float* __restrict__ MWih, const float* __restrict__ MWhh,
    const float* __restrict__ UWih, const float* __restrict__ UWhh,
    const float* __restrict__ EnW1, const float* __restrict__ EnW2,
    const float* __restrict__ EeW1, const float* __restrict__ EeW2,
    const float* __restrict__ MBih, const float* __restrict__ MBhh,
    const float* __restrict__ UBih, const float* __restrict__ UBhh,
    const float* __restrict__ GWih, const float* __restrict__ GWhh,
    const float* __restrict__ GBih, const float* __restrict__ GBhh,
    ush* __restrict__ xh, ush* __restrict__ WPQ, ush* __restrict__ WTh,
    ush* __restrict__ WTu, ush* __restrict__ WBen1, ush* __restrict__ WBen2,
    ush* __restrict__ WBee1, ush* __restrict__ WBee2,
    float* __restrict__ biasM, float* __restrict__ biasU,
    float* __restrict__ WT_G, float* __restrict__ biasG, ush* __restrict__ bn2rep)
{
  const int b = blockIdx.x, t = threadIdx.x;
  if (b < 2048) {                       // xh towers part: 32768*16
    const int idx = b * 256 + t;
    const int row = idx >> 4, kk = idx & 15;
    xh[row * 144 + kk] = f2u(kk < 14 ? towers[row * 14 + kk] : 0.f);
  } else if (b < 2528) {                // WPQ: 5*768*32
    const int idx = (b - 2048) * 256 + t;
    const int ck = idx / 24576, rem = idx % 24576, n = rem >> 5, kk = rem & 31;
    const int k = ck * 32 + kk;
    const int half = (n >= 384);
    const int m = n - half * 384;
    const int g = m >> 7, c = m & 127;
    const int row = g * 128 + c;
    int col = -1;
    if (k < 14)                  col = k;
    else if (k >= 16 && k < 144) col = k - 2;
    if (half && col >= 0)        col += 142;
    WPQ[idx] = f2u((col >= 0) ? MWih[row * 284 + col] : 0.f);
  } else if (b < 2720) {                // WTh: 4*384*32
    const int idx = (b - 2528) * 256 + t;
    const int ck = idx / 12288, rem = idx % 12288, n = rem >> 5, kk = rem & 31;
    const int g = n >> 7, c = n & 127;
    WTh[idx] = f2u(MWhh[(g * 128 + c) * 128 + ck * 32 + kk]);
  } else if (b < 3296) {                // WTu: 9*512*32 swizzled
    const int idx = (b - 2720) * 256 + t;
    const int ck = idx >> 14, n = (idx >> 5) & 511, kk = idx & 31;
    const int k = ck * 32 + kk, gate = n >> 7, c = n & 127;
    float w = 0.f;
    const int row = (gate == 0) ? c : (gate == 1) ? 128 + c : 256 + c;
    if (k < 160) {
      int col = -1;
      if (k < 16)        { if (k < 14) col = k; }
      else if (k < 144)  col = 14 + (k - 16);
      if (gate != 3 && col >= 0) w = UWih[row * 142 + col];
    } else {
      if (gate != 2) w = UWhh[row * 128 + (k - 160)];
    }
    WTu[ck * 16384 + swz_idx(n, kk)] = f2u(w);
  } else if (b < 3312) {                // WBen1: 128x14 pad32
    const int idx = (b - 3296) * 256 + t;
    const int n = (idx >> 5) & 127, kk = idx & 31;
    WBen1[swz_idx(n, kk)] = f2u(kk < 14 ? EnW1[n * 14 + kk] : 0.f);
  } else if (b < 3376) {                // WBen2: 128x128
    const int idx = (b - 3312) * 256 + t;
    const int ck = idx >> 12, n = (idx >> 5) & 127, kk = idx & 31;
    WBen2[ck * 4096 + swz_idx(n, kk)] = f2u(EnW2[n * 128 + ck * 32 + kk]);
  } else if (b < 3392) {                // WBee1: 128x28 pair
    const int idx = (b - 3376) * 256 + t;
    const int n = (idx >> 5) & 127, kk = idx & 31;
    int col = (kk < 16) ? (kk < 14 ? kk : -1) : (kk < 30 ? 14 + (kk - 16) : -1);
    WBee1[swz_idx(n, kk)] = f2u(col >= 0 ? EeW1[n * 28 + col] : 0.f);
  } else if (b < 3456) {                // WBee2: 128x128
    const int idx = (b - 3392) * 256 + t;
    const int ck = idx >> 12, n = (idx >> 5) & 127, kk = idx & 31;
    WBee2[ck * 4096 + swz_idx(n, kk)] = f2u(EeW2[n * 128 + ck * 32 + kk]);
  } else if (b < 3458) {                // biasM [4 gates][128]
    const int idx = (b - 3456) * 256 + t;
    const int g = idx >> 7, c = idx & 127;
    float v;
    if (g == 0)      v = MBih[c] + MBhh[c];
    else if (g == 1) v = MBih[128 + c] + MBhh[128 + c];
    else if (g == 2) v = MBih[256 + c];
    else             v = MBhh[256 + c];
    biasM[idx] = v;
  } else if (b < 3460) {                // biasU
    const int idx = (b - 3458) * 256 + t;
    const int g = idx >> 7, c = idx & 127;
    float v;
    if (g == 0)      v = UBih[c] + UBhh[c];
    else if (g == 1) v = UBih[128 + c] + UBhh[128 + c];
    else if (g == 2) v = UBih[256 + c];
    else             v = UBhh[256 + c];
    biasU[idx] = v;
  } else if (b < 4228) {                // WT_G interleaved fp32: 384*512
    const int idx = (b - 3460) * 256 + t;
    const int kc = idx >> 9, cg = (idx >> 2) & 127, gate = idx & 3;
    const int row = (gate == 0) ? cg : (gate == 1) ? cg + 128 : cg + 256;
    float v = 0.f;
    if (kc < 256) { if (gate != 3) v = GWih[row * 256 + kc]; }
    else          { if (gate != 2) v = GWhh[row * 128 + (kc - 256)]; }
    WT_G[idx] = v;
  } else if (b < 4230) {                // biasG
    const int idx = (b - 4228) * 256 + t;
    const int cg = idx >> 2, gate = idx & 3;
    float v;
    if (gate == 0)      v = GBih[cg] + GBhh[cg];
    else if (gate == 1) v = GBih[cg + 128] + GBhh[cg + 128];
    else if (gate == 2) v = GBih[cg + 256];
    else                v = GBhh[cg + 256];
    biasG[idx] = v;
  } else {                              // bn2rep: [128][8] = bhh_n replicated
    const int idx = (b - 4230) * 256 + t;   // 1024
    bn2rep[idx] = f2u(MBhh[256 + (idx >> 3)]);
  }
}

// ---------------------------------------------------------------------------
// PQ GEMM: per-graph transposed store PqT[g][768][8] bf16.
// Block = 64 rows x 384 cols (blockIdx.y = P/Q half); wave = 96 cols.
// ---------------------------------------------------------------------------
__global__ __launch_bounds__(256, 2) void pq_mfma(
    const ush* __restrict__ xh, const ush* __restrict__ WPQ,
    const float* __restrict__ biasM, ush* __restrict__ PqT)
{
  __shared__ ush As[5 * 64 * 32];
  const int t = threadIdx.x, lane = t & 63, w = t >> 6;
  const int rowBase = blockIdx.x * 64, half = blockIdx.y;
  const int gm = t >> 2, gb = t & 3, grow = rowBase + gm;

  #pragma unroll
  for (int ck = 0; ck < 5; ++ck) {
    const int k0 = ck * 32 + gb * 8;
    s16x8 v = z8();
    if (k0 < 144) v = *(const s16x8*)(xh + grow * 144 + k0);
    *(s16x8*)&As[ck * 2048 + swz_blk(gm, gb)] = v;
  }
  __syncthreads();

  f32x4 acc[6][4];
  #pragma unroll
  for (int tl = 0; tl < 6; ++tl)
    #pragma unroll
    for (int rt = 0; rt < 4; ++rt) {
      #pragma unroll
      for (int q = 0; q < 4; ++q) acc[tl][rt][q] = 0.f;
    }

  for (int ck = 0; ck < 5; ++ck) {
    s16x8 af[4];
    #pragma unroll
    for (int rt = 0; rt < 4; ++rt)
      af[rt] = *(const s16x8*)&As[ck * 2048 + swz_blk(rt * 16 + (lane & 15), lane >> 4)];
    #pragma unroll
    for (int tl = 0; tl < 6; ++tl) {
      const int n = w * 96 + tl * 16 + (lane & 15);
      const s16x8 bf = *(const s16x8*)&WPQ[(ck * 768 + half * 384 + n) * 32 + (lane >> 4) * 8];
      #pragma unroll
      for (int rt = 0; rt < 4; ++rt) acc[tl][rt] = MFMA(af[rt], bf, acc[tl][rt]);
    }
  }

  #pragma unroll
  for (int tl = 0; tl < 6; ++tl) {
    const int col = w * 96 + tl * 16 + (lane & 15);      // 0..383 within half
    const float bv = half ? 0.f : biasM[col];
    #pragma unroll
    for (int rt = 0; rt < 4; ++rt) {
      const int row0 = rowBase + rt * 16 + (lane >> 4) * 4;   // 4-aligned
      const int g = row0 >> 3, n0 = row0 & 7;                 // n0 in {0,4}
      u16x4 wv;
      #pragma unroll
      for (int q = 0; q < 4; ++q) wv[q] = f2u(acc[tl][rt][q] + bv);
      *(u16x4*)&PqT[(g * 768 + half * 384 + col) * 8 + n0] = wv;
    }
  }
}

// ---------------------------------------------------------------------------
// Edge GRU (transposed-C): block = 1 graph = 64 edge rows.
// A = WTh / PqT / bn2rep (m = gate col), B = eh LDS tile / in-reg indicator
// (n = edge row). Lane holds 4 consecutive hcols -> packed epilogue.
// ---------------------------------------------------------------------------
__global__ __launch_bounds__(256, 2) void edge_mfma(
    ush* __restrict__ eh, const ush* __restrict__ WTh,
    const ush* __restrict__ PqT, const ush* __restrict__ bn2rep)
{
  __shared__ ush As[4 * 64 * 32];     // e_h 64x128 swizzled (B operand + hp)
  const int t = threadIdx.x, lane = t & 63, w = t >> 6;
  const int g = blockIdx.x, rowBase = g * 64;
  const int quad = lane >> 4, l15 = lane & 15;

  {
    const int gm = t >> 2, gb = t & 3;
    #pragma unroll
    for (int ck = 0; ck < 4; ++ck) {
      const s16x8 v = *(const s16x8*)(eh + (rowBase + gm) * 128 + ck * 32 + gb * 8);
      *(s16x8*)&As[ck * 2048 + swz_blk(gm, gb)] = v;
    }
  }
  __syncthreads();

  // acc[mt][nt]: mt = hcol tile (2 of 16), nt = edge-row tile (4 of 16)
  f32x4 accR[2][4], accZ[2][4], accN1[2][4], accN2[2][4];
  #pragma unroll
  for (int mt = 0; mt < 2; ++mt)
    #pragma unroll
    for (int nt = 0; nt < 4; ++nt) {
      #pragma unroll
      for (int q = 0; q < 4; ++q) { accR[mt][nt][q] = 0.f; accZ[mt][nt][q] = 0.f; accN1[mt][nt][q] = 0.f; accN2[mt][nt][q] = 0.f; }
    }

  // main h-phase: D += WTh · eh^T   (gates r, z, n2)
  #pragma unroll
  for (int ck = 0; ck < 4; ++ck) {
    s16x8 be[4];
    #pragma unroll
    for (int nt = 0; nt < 4; ++nt)
      be[nt] = *(const s16x8*)&As[ck * 2048 + swz_blk(nt * 16 + l15, quad)];
    #pragma unroll
    for (int mt = 0; mt < 2; ++mt) {
      const int nb = w * 32 + mt * 16 + l15;
      const int ko = quad * 8;
      const s16x8 aR = *(const s16x8*)&WTh[(ck * 384 + nb) * 32 + ko];
      const s16x8 aZ = *(const s16x8*)&WTh[(ck * 384 + 128 + nb) * 32 + ko];
      const s16x8 aN = *(const s16x8*)&WTh[(ck * 384 + 256 + nb) * 32 + ko];
      #pragma unroll
      for (int nt = 0; nt < 4; ++nt) {
        accR[mt][nt]  = MFMA(aR, be[nt], accR[mt][nt]);
        accZ[mt][nt]  = MFMA(aZ, be[nt], accZ[mt][nt]);
        accN2[mt][nt] = MFMA(aN, be[nt], accN2[mt][nt]);
      }
    }
  }

  // indicator chunk: A from PqT (k<8 -> P[node], k 8..15 -> Q[node]),
  // B = in-register one-hot of (i, j) per edge row.
  {
    s16x8 bI[4];
    #pragma unroll
    for (int nt = 0; nt < 4; ++nt) {
      const int erow = nt * 16 + l15;
      s16x8 v = z8();
      if (quad == 0)      v[erow >> 3] = (short)0x3F80;   // k=i -> P select
      else if (quad == 1) v[erow & 7]  = (short)0x3F80;   // k=8+j -> Q select
      bI[nt] = v;
    }
    #pragma unroll
    for (int mt = 0; mt < 2; ++mt) {
      const int c = w * 32 + mt * 16 + l15;
      s16x8 aR = z8(), aZ = z8(), aN1 = z8(), aN2 = z8();
      if (quad == 0) {
        const ush* base = PqT + (size_t)g * 768 * 8;
        aR  = *(const s16x8*)&base[(c) * 8];
        aZ  = *(const s16x8*)&base[(128 + c) * 8];
        aN1 = *(const s16x8*)&base[(256 + c) * 8];
        aN2 = *(const s16x8*)&bn2rep[c * 8];
      } else if (quad == 1) {
        const ush* base = PqT + ((size_t)g * 768 + 384) * 8;
        aR  = *(const s16x8*)&base[(c) * 8];
        aZ  = *(const s16x8*)&base[(128 + c) * 8];
        aN1 = *(const s16x8*)&base[(256 + c) * 8];
      }
      #pragma unroll
      for (int nt = 0; nt < 4; ++nt) {
        accR[mt][nt]  = MFMA(aR,  bI[nt], accR[mt][nt]);
        accZ[mt][nt]  = MFMA(aZ,  bI[nt], accZ[mt][nt]);
        accN1[mt][nt] = MFMA(aN1, bI[nt], accN1[mt][nt]);
        accN2[mt][nt] = MFMA(aN2, bI[nt], accN2[mt][nt]);
      }
    }
  }

  // epilogue: lane owns (edgerow = nt*16+l15, hcols = w*32+mt*16+quad*4 .. +3)
  #pragma unroll
  for (int mt = 0; mt < 2; ++mt) {
    const int hc0 = w * 32 + mt * 16 + quad * 4;
    const int ck2 = hc0 >> 5, kkB = hc0 & 31;
    #pragma unroll
    for (int nt = 0; nt < 4; ++nt) {
      const int erow = nt * 16 + l15;
      const u16x4 hp4 = *(const u16x4*)&As[ck2 * 2048 + swz_blk(erow, kkB >> 3) + (kkB & 7)];
      u16x4 ov;
      #pragma unroll
      for (int q = 0; q < 4; ++q) {
        const float rg = sigmoid_f(accR[mt][nt][q]);
        const float zg = sigmoid_f(accZ[mt][nt][q]);
        const float nn = tanh_f(accN1[mt][nt][q] + rg * accN2[mt][nt][q]);
        const float hp = u2f(hp4[q]);
        ov[q] = f2u(nn + zg * (hp - nn));
      }
      *(u16x4*)&eh[(rowBase + erow) * 128 + hc0] = ov;
    }
  }
}

// ---------------------------------------------------------------------------
// Node GRU (MFMA): 64 rows x 512 gate-cols per block.
// ---------------------------------------------------------------------------
__global__ __launch_bounds__(256, 2) void gru_node(
    ush* __restrict__ xh, const ush* __restrict__ eh,
    const ush* __restrict__ WT, const float* __restrict__ bias)
{
  constexpr int NCH = 9, XCH = 5;
  __shared__ ush As[64 * 32];
  __shared__ ush Bs[512 * 32];
  const int t = threadIdx.x, lane = t & 63, w = t >> 6;
  const int rowBase = blockIdx.x * 64;
  const int gm = t >> 2, gb = t & 3, grow = rowBase + gm;

  f32x4 accR[4][2], accZ[4][2], accN1[4][2], accN2[4][2];
  #pragma unroll
  for (int rt = 0; rt < 4; ++rt)
    #pragma unroll
    for (int s = 0; s < 2; ++s) {
      #pragma unroll
      for (int q = 0; q < 4; ++q) { accR[rt][s][q] = 0.f; accZ[rt][s][q] = 0.f; accN1[rt][s][q] = 0.f; accN2[rt][s][q] = 0.f; }
    }

  for (int ck = 0; ck < NCH; ++ck) {
    const ush* wsrc = WT + ck * 16384;
    #pragma unroll
    for (int ii = 0; ii < 8; ++ii) {
      const int o = (t + ii * 256) * 8;
      *(s16x8*)&Bs[o] = *(const s16x8*)&wsrc[o];
    }
    {
      const int k0 = ck * 32 + gb * 8;
      s16x8 v = z8();
      if (k0 < 16)       v = *(const s16x8*)(xh + grow * 144 + k0);
      else if (k0 < 144) {
        const int i = grow & 7;
        if (i < 7) v = *(const s16x8*)(eh + (grow * 8 + i + 1) * 128 + (k0 - 16));
      } else if (k0 >= 160) {
        v = *(const s16x8*)(xh + grow * 144 + 16 + (k0 - 160));
      }
      *(s16x8*)&As[swz_blk(gm, gb)] = v;
    }
    __syncthreads();

    s16x8 af[4];
    #pragma unroll
    for (int rt = 0; rt < 4; ++rt)
      af[rt] = *(const s16x8*)&As[swz_blk(rt * 16 + (lane & 15), lane >> 4)];
    if (ck < XCH) {
      #pragma unroll
      for (int s = 0; s < 2; ++s) {
        const int nb = w * 32 + s * 16 + (lane & 15);
        const s16x8 bR = *(const s16x8*)&Bs[swz_blk(0 * 128 + nb, lane >> 4)];
        const s16x8 bZ = *(const s16x8*)&Bs[swz_blk(1 * 128 + nb, lane >> 4)];
        const s16x8 bN = *(const s16x8*)&Bs[swz_blk(2 * 128 + nb, lane >> 4)];
        #pragma unroll
        for (int rt = 0; rt < 4; ++rt) {
          accR[rt][s]  = MFMA(af[rt], bR, accR[rt][s]);
          accZ[rt][s]  = MFMA(af[rt], bZ, accZ[rt][s]);
          accN1[rt][s] = MFMA(af[rt], bN, accN1[rt][s]);
        }
      }
    } else {
      #pragma unroll
      for (int s = 0; s < 2; ++s) {
        const int nb = w * 32 + s * 16 + (lane & 15);
        const s16x8 bR = *(const s16x8*)&Bs[swz_blk(0 * 128 + nb, lane >> 4)];
        const s16x8 bZ = *(const s16x8*)&Bs[swz_blk(1 * 128 + nb, lane >> 4)];
        const s16x8 bN = *(const s16x8*)&Bs[swz_blk(3 * 128 + nb, lane >> 4)];
        #pragma unroll
        for (int rt = 0; rt < 4; ++rt) {
          accR[rt][s]  = MFMA(af[rt], bR, accR[rt][s]);
          accZ[rt][s]  = MFMA(af[rt], bZ, accZ[rt][s]);
          accN2[rt][s] = MFMA(af[rt], bN, accN2[rt][s]);
        }
      }
    }
    __syncthreads();
  }

  #pragma unroll
  for (int s = 0; s < 2; ++s) {
    const int hcol = w * 32 + s * 16 + (lane & 15);
    const float bR = bias[hcol], bZ = bias[128 + hcol], bN1 = bias[256 + hcol], bN2 = bias[384 + hcol];
    #pragma unroll
    for (int rt = 0; rt < 4; ++rt) {
      #pragma unroll
      for (int q = 0; q < 4; ++q) {
        const int row = rowBase + rt * 16 + (lane >> 4) * 4 + q;
        const float hp = u2f(xh[row * 144 + 16 + hcol]);
        const float rg = sigmoid_f(accR[rt][s][q] + bR);
        const float zg = sigmoid_f(accZ[rt][s][q] + bZ);
        const float nn = tanh_f(accN1[rt][s][q] + bN1 + rg * (accN2[rt][s][q] + bN2));
        xh[row * 144 + 16 + hcol] = f2u(nn + zg * (hp - nn));
      }
    }
  }
}

// ---------------------------------------------------------------------------
// MFMA 2-layer tanh encoder. MODE 0 = En, MODE 1 = Ee.
// ---------------------------------------------------------------------------
template<int MODE>
__global__ __launch_bounds__(256, 2) void enc_mfma(
    ush* __restrict__ xh, ush* __restrict__ eh,
    const ush* __restrict__ WB1, const float* __restrict__ b1,
    const ush* __restrict__ WB2, const float* __restrict__ b2)
{
  __shared__ ush A1[64 * 32];
  __shared__ ush Z1[4 * 64 * 32];
  __shared__ ush B1s[128 * 32];
  __shared__ ush B2s[4 * 128 * 32];
  const int t = threadIdx.x, lane = t & 63, w = t >> 6;
  const int rowBase = blockIdx.x * 64;

  #pragma unroll
  for (int ii = 0; ii < 2; ++ii) { const int o = (t + ii * 256) * 8; *(s16x8*)&B1s[o] = *(const s16x8*)&WB1[o]; }
  #pragma unroll
  for (int ii = 0; ii < 8; ++ii) { const int o = (t + ii * 256) * 8; *(s16x8*)&B2s[o] = *(const s16x8*)&WB2[o]; }
  {
    const int gm = t >> 2, gb = t & 3, grow = rowBase + gm;
    s16x8 v = z8();
    if (MODE == 0) {
      if (gb < 2) v = *(const s16x8*)(xh + grow * 144 + gb * 8);
    } else {
      const int n = grow >> 6, i = (grow >> 3) & 7, j = grow & 7;
      v = (gb < 2) ? *(const s16x8*)(xh + (n * 8 + i) * 144 + gb * 8)
                   : *(const s16x8*)(xh + (n * 8 + j) * 144 + (gb - 2) * 8);
    }
    *(s16x8*)&A1[swz_blk(gm, gb)] = v;
  }
  __syncthreads();

  s16x8 af[4];
  #pragma unroll
  for (int rt = 0; rt < 4; ++rt)
    af[rt] = *(const s16x8*)&A1[swz_blk(rt * 16 + (lane & 15), lane >> 4)];
  f32x4 acc1[4][2];
  #pragma unroll
  for (int rt = 0; rt < 4; ++rt)
    #pragma unroll
    for (int ct = 0; ct < 2; ++ct) {
      #pragma unroll
      for (int q = 0; q < 4; ++q) acc1[rt][ct][q] = 0.f;
    }
  #pragma unroll
  for (int ct = 0; ct < 2; ++ct) {
    const int n = w * 32 + ct * 16 + (lane & 15);
    const s16x8 bf = *(const s16x8*)&B1s[swz_blk(n, lane >> 4)];
    #pragma unroll
    for (int rt = 0; rt < 4; ++rt) acc1[rt][ct] = MFMA(af[rt], bf, acc1[rt][ct]);
  }
  #pragma unroll
  for (int ct = 0; ct < 2; ++ct) {
    const int col = w * 32 + ct * 16 + (lane & 15);
    const int ck2 = col >> 5, kk = col & 31;
    #pragma unroll
    for (int rt = 0; rt < 4; ++rt) {
      #pragma unroll
      for (int q = 0; q < 4; ++q) {
        const int m = rt * 16 + (lane >> 4) * 4 + q;
        Z1[ck2 * 2048 + swz_idx(m, kk)] = f2u(tanh_f(acc1[rt][ct][q] + b1[col]));
      }
    }
  }
  __syncthreads();

  f32x4 acc2[4][2];
  #pragma unroll
  for (int rt = 0; rt < 4; ++rt)
    #pragma unroll
    for (int ct = 0; ct < 2; ++ct) {
      #pragma unroll
      for (int q = 0; q < 4; ++q) acc2[rt][ct][q] = 0.f;
    }
  for (int ck2 = 0; ck2 < 4; ++ck2) {
    #pragma unroll
    for (int rt = 0; rt < 4; ++rt)
      af[rt] = *(const s16x8*)&Z1[ck2 * 2048 + swz_blk(rt * 16 + (lane & 15), lane >> 4)];
    #pragma unroll
    for (int ct = 0; ct < 2; ++ct) {
      const int n = w * 32 + ct * 16 + (lane & 15);
      const s16x8 bf = *(const s16x8*)&B2s[ck2 * 4096 + swz_blk(n, lane >> 4)];
      #pragma unroll
      for (int rt = 0; rt < 4; ++rt) acc2[rt][ct] = MFMA(af[rt], bf, acc2[rt][ct]);
    }
  }
  #pragma unroll
  for (int ct = 0; ct < 2; ++ct) {
    const int col = w * 32 + ct * 16 + (lane & 15);
    #pragma unroll
    for (int rt = 0; rt < 4; ++rt) {
      #pragma unroll
      for (int q = 0; q < 4; ++q) {
        const int row = rowBase + rt * 16 + (lane >> 4) * 4 + q;
        const float v = tanh_f(acc2[rt][ct][q] + b2[col]);
        if (MODE == 0) xh[row * 144 + 16 + col] = f2u(v);
        else           eh[row * 128 + col] = f2u(v);
      }
    }
  }
}

// ---------------------------------------------------------------------------
// readout path
// ---------------------------------------------------------------------------
__global__ __launch_bounds__(256) void sums2(const ush* __restrict__ xh, const ush* __restrict__ eh,
                                             float* __restrict__ hsum, float* __restrict__ esum) {
  const int idx = blockIdx.x * 256 + threadIdx.x;    // 4096*128
  const int n = idx >> 7, hh = idx & 127;
  float hs = 0.f, es = 0.f;
  #pragma unroll
  for (int i = 0; i < 8; ++i) hs += u2f(xh[(n * 8 + i) * 144 + 16 + hh]);
  #pragma unroll
  for (int i = 0; i < 7; ++i) es += u2f(eh[((n * 8 + i) * 8 + i + 1) * 128 + hh]);
  hsum[idx] = hs;
  esum[idx] = es;
}

// global GRU (h_prev = 0) fused with output head: 16 graphs per block.
__global__ __launch_bounds__(256) void gru_global_out(
    const float* __restrict__ hsum, const float* __restrict__ esum,
    const float* __restrict__ WT, const float* __restrict__ bias,
    const float* __restrict__ OW, const float* __restrict__ Ob,
    float* __restrict__ out)
{
  constexpr int KT = 384;
  __shared__ float4 ATl4[KT * 4];
  __shared__ float4 Bl4[16 * 128];
  __shared__ float gmat[16 * 128];
  __shared__ float red[16 * 4];
  float* ATl = (float*)ATl4;
  const int t = threadIdx.x;
  const int rowBase = blockIdx.x * 16;
  for (int idx = t; idx < KT * 16; idx += 256) {
    const int kc = idx >> 4, r = idx & 15, grow = rowBase + r;
    float v = 0.f;
    if (kc < 128)      v = hsum[grow * 128 + kc];
    else if (kc < 256) v = esum[grow * 128 + (kc - 128)];
    ATl[idx] = v;
  }
  const int c = t & 127, rh = t >> 7;
  float accR[8], accZ[8], accN1[8];
  #pragma unroll
  for (int rr = 0; rr < 8; ++rr) { accR[rr] = 0.f; accZ[rr] = 0.f; accN1[rr] = 0.f; }
  const float4* WT4 = (const float4*)WT;
  for (int ck = 0; ck < 16; ++ck) {
    __syncthreads();
    #pragma unroll
    for (int ii = 0; ii < 8; ++ii) { const int idx = t + ii * 256; Bl4[idx] = WT4[ck * 2048 + idx]; }
    __syncthreads();
    const int kb = ck * 16;
    #pragma unroll
    for (int kcl = 0; kcl < 16; ++kcl) {
      const float4 wv = Bl4[kcl * 128 + c];
      const float4 a0 = ATl4[(kb + kcl) * 4 + rh * 2];
      const float4 a1 = ATl4[(kb + kcl) * 4 + rh * 2 + 1];
      const float av[8] = {a0.x, a0.y, a0.z, a0.w, a1.x, a1.y, a1.z, a1.w};
      #pragma unroll
      for (int rr = 0; rr < 8; ++rr) {
        accR[rr]  += wv.x * av[rr];
        accZ[rr]  += wv.y * av[rr];
        accN1[rr] += wv.z * av[rr];
      }
    }
  }
  const float4 bb = ((const float4*)bias)[c];
  const float ow = OW[c];
  #pragma unroll
  for (int rr = 0; rr < 8; ++rr) {
    const float rg = sigmoid_f(accR[rr] + bb.x);
    const float zg = sigmoid_f(accZ[rr] + bb.y);
    const float nn = tanh_f(accN1[rr] + bb.z + rg * bb.w);
    gmat[(rh * 8 + rr) * 128 + c] = (1.f - zg) * nn * ow;
  }
  __syncthreads();
  if (t < 64) {
    const int r = t >> 2, part = t & 3;
    float s = 0.f;
    #pragma unroll
    for (int cc = 0; cc < 32; ++cc) s += gmat[r * 128 + part * 32 + cc];
    red[r * 4 + part] = s;
  }
  __syncthreads();
  if (t < 16) {
    const float s = red[t * 4] + red[t * 4 + 1] + red[t * 4 + 2] + red[t * 4 + 3];
    out[rowBase + t] = sigmoid_f(s + Ob[0]);
  }
}

// ---------------------------------------------------------------------------
extern "C" void kernel_launch(void* const* d_in, const int* in_sizes, int n_in,
                              void* d_out, int out_size, void* d_ws, size_t ws_size,
                              hipStream_t stream)
{
  (void)in_sizes; (void)n_in; (void)out_size; (void)ws_size;
  const float* towers = (const float*)d_in[0];
  const float* EnW1 = (const float*)d_in[1];
  const float* EnB1 = (const float*)d_in[2];
  const float* EnW2 = (const float*)d_in[3];
  const float* EnB2 = (const float*)d_in[4];
  const float* EeW1 = (const float*)d_in[5];
  const float* EeB1 = (const float*)d_in[6];
  const float* EeW2 = (const float*)d_in[7];
  const float* EeB2 = (const float*)d_in[8];
  const float* UWih = (const float*)d_in[9];
  const float* UWhh = (const float*)d_in[10];
  const float* UBih = (const float*)d_in[11];
  const float* UBhh = (const float*)d_in[12];
  const float* MWih = (const float*)d_in[13];
  const float* MWhh = (const float*)d_in[14];
  const float* MBih = (const float*)d_in[15];
  const float* MBhh = (const float*)d_in[16];
  const float* GWih = (const float*)d_in[17];
  const float* GWhh = (const float*)d_in[18];
  const float* GBih = (const float*)d_in[19];
  const float* GBhh = (const float*)d_in[20];
  const float* OW   = (const float*)d_in[21];
  const float* Ob   = (const float*)d_in[22];

  char* ws = (char*)d_ws;
  size_t off = 0;
  auto take = [&](size_t b) { void* p = ws + off; off = (off + b + 255) & ~(size_t)255; return p; };
  ush*   xh     = (ush*)take((size_t)32768 * 144 * 2);
  ush*   eh     = (ush*)take((size_t)262144 * 128 * 2);
  ush*   PqT    = (ush*)take((size_t)4096 * 768 * 8 * 2);
  float* hsum   = (float*)take((size_t)4096 * 128 * 4);
  float* esum   = (float*)take((size_t)4096 * 128 * 4);
  ush*   WPQ    = (ush*)take((size_t)5 * 768 * 32 * 2);
  ush*   WTh    = (ush*)take((size_t)4 * 384 * 32 * 2);
  ush*   WTu    = (ush*)take((size_t)9 * 512 * 32 * 2);
  ush*   WBen1  = (ush*)take((size_t)128 * 32 * 2);
  ush*   WBen2  = (ush*)take((size_t)4 * 128 * 32 * 2);
  ush*   WBee1  = (ush*)take((size_t)128 * 32 * 2);
  ush*   WBee2  = (ush*)take((size_t)4 * 128 * 32 * 2);
  float* biasM  = (float*)take(512 * 4);
  float* biasU  = (float*)take(512 * 4);
  float* WT_G   = (float*)take((size_t)384 * 512 * 4);
  float* biasG  = (float*)take(512 * 4);
  ush*   bn2rep = (ush*)take(128 * 8 * 2);

  // ---- all weight/state prep in one launch ----
  prep_all<<<4234, 256, 0, stream>>>(
      towers, MWih, MWhh, UWih, UWhh, EnW1, EnW2, EeW1, EeW2,
      MBih, MBhh, UBih, UBhh, GWih, GWhh, GBih, GBhh,
      xh, WPQ, WTh, WTu, WBen1, WBen2, WBee1, WBee2,
      biasM, biasU, WT_G, biasG, bn2rep);

  // ---- encoders ----
  enc_mfma<0><<<512, 256, 0, stream>>>(xh, eh, WBen1, EnB1, WBen2, EnB2);
  enc_mfma<1><<<4096, 256, 0, stream>>>(xh, eh, WBee1, EeB1, WBee2, EeB2);

  // ---- k = 3 message-passing iterations ----
  for (int it = 0; it < 3; ++it) {
    pq_mfma<<<dim3(512, 2), 256, 0, stream>>>(xh, WPQ, biasM, PqT);
    edge_mfma<<<4096, 256, 0, stream>>>(eh, WTh, PqT, bn2rep);
    gru_node<<<512, 256, 0, stream>>>(xh, eh, WTu, biasU);
  }

  // ---- global readout ----
  sums2<<<2048, 256, 0, stream>>>(xh, eh, hsum, esum);
  gru_global_out<<<256, 256, 0, stream>>>(hsum, esum, WT_G, biasG, OW, Ob, (float*)d_out);
}

// Round 9
// 445.657 us; speedup vs baseline: 1.5788x; 1.1085x over previous
//
#include <hip/hip_runtime.h>
#include <hip/hip_bf16.h>

typedef __hip_bfloat16 bf16;
typedef unsigned short ush;
typedef short s16x8 __attribute__((ext_vector_type(8)));
typedef ush u16x4 __attribute__((ext_vector_type(4)));
typedef float f32x4 __attribute__((ext_vector_type(4)));

#define DEV __device__ __forceinline__

DEV float rcp_f(float x) { return __builtin_amdgcn_rcpf(x); }
DEV float sigmoid_f(float x) { return rcp_f(1.f + __expf(-x)); }
DEV float tanh_f(float x) { return 1.f - 2.f * rcp_f(__expf(2.f * x) + 1.f); }

DEV float u2f(ush u) { unsigned int v = ((unsigned int)u) << 16; float f; __builtin_memcpy(&f, &v, 4); return f; }
DEV ush f2u(float f) { bf16 h = __float2bfloat16(f); ush u; __builtin_memcpy(&u, &h, 2); return u; }

DEV f32x4 MFMA(s16x8 a, s16x8 b, f32x4 c) {
  return __builtin_amdgcn_mfma_f32_16x16x32_bf16(a, b, c, 0, 0, 0);
}

DEV s16x8 z8() {
  s16x8 v;
  for (int z = 0; z < 8; ++z) v[z] = 0;
  return v;
}

// swizzled element index within a [rows][32] bf16 chunk: 16B blocks XOR'd by (row>>1)&3
DEV int swz_idx(int row, int kk) { return row * 32 + (((kk >> 3) ^ ((row >> 1) & 3)) << 3) + (kk & 7); }
DEV int swz_blk(int row, int blk) { return row * 32 + ((blk ^ ((row >> 1) & 3)) << 3); }

// ---------------------------------------------------------------------------
// N=4096 graphs, K=8 nodes, n_in=14, H=128, k=3 iters. Inputs fp32.
// xh:  [32768][144] bf16 = [towers(14), pad(2), h(128)]
// eh:  [262144][128] bf16 (e_h^0 never hits HBM: computed inline in edge-0)
// PqT: [4096][768][8] bf16, produced fused in enc_en_pq / gru_node_pq.
// Edge GRU (transposed-C): D[gatecol][edgerow] = WTh·eh^T + indicator chunk
// (A=PqT/bn2rep, B=in-reg one-hot of (i,j)) -> P[i]+Q[j]+bias pre-added.
// ---------------------------------------------------------------------------

__global__ __launch_bounds__(256) void prep_all(
    const float* __restrict__ towers,
    const float* __restrict__ MWih, const float* __restrict__ MWhh,
    const float* __restrict__ UWih, const float* __restrict__ UWhh,
    const float* __restrict__ EnW1, const float* __restrict__ EnW2,
    const float* __restrict__ EeW1, const float* __restrict__ EeW2,
    const float* __restrict__ MBih, const float* __restrict__ MBhh,
    const float* __restrict__ UBih, const float* __restrict__ UBhh,
    const float* __restrict__ GWih, const float* __restrict__ GWhh,
    const float* __restrict__ GBih, const float* __restrict__ GBhh,
    ush* __restrict__ xh, ush* __restrict__ WPQ, ush* __restrict__ WTh,
    ush* __restrict__ WTu, ush* __restrict__ WBen1, ush* __restrict__ WBen2,
    ush* __restrict__ WBee1, ush* __restrict__ WBee2,
    float* __restrict__ biasM, float* __restrict__ biasU,
    float* __restrict__ WT_G, float* __restrict__ biasG, ush* __restrict__ bn2rep)
{
  const int b = blockIdx.x, t = threadIdx.x;
  if (b < 2048) {                       // xh towers part: 32768*16
    const int idx = b * 256 + t;
    const int row = idx >> 4, kk = idx & 15;
    xh[row * 144 + kk] = f2u(kk < 14 ? towers[row * 14 + kk] : 0.f);
  } else if (b < 2528) {                // WPQ: 5*768*32 linear fragment layout
    const int idx = (b - 2048) * 256 + t;
    const int ck = idx / 24576, rem = idx % 24576, n = rem >> 5, kk = rem & 31;
    const int k = ck * 32 + kk;
    const int half = (n >= 384);
    const int m = n - half * 384;
    const int g = m >> 7, c = m & 127;
    const int row = g * 128 + c;
    int col = -1;
    if (k < 14)                  col = k;
    else if (k >= 16 && k < 144) col = k - 2;
    if (half && col >= 0)        col += 142;
    WPQ[idx] = f2u((col >= 0) ? MWih[row * 284 + col] : 0.f);
  } else if (b < 2720) {                // WTh: 4*384*32 linear
    const int idx = (b - 2528) * 256 + t;
    const int ck = idx / 12288, rem = idx % 12288, n = rem >> 5, kk = rem & 31;
    const int g = n >> 7, c = n & 127;
    WTh[idx] = f2u(MWhh[(g * 128 + c) * 128 + ck * 32 + kk]);
  } else if (b < 3296) {                // WTu: 9*512*32 swizzled (LDS-staged)
    const int idx = (b - 2720) * 256 + t;
    const int ck = idx >> 14, n = (idx >> 5) & 511, kk = idx & 31;
    const int k = ck * 32 + kk, gate = n >> 7, c = n & 127;
    float w = 0.f;
    const int row = (gate == 0) ? c : (gate == 1) ? 128 + c : 256 + c;
    if (k < 160) {
      int col = -1;
      if (k < 16)        { if (k < 14) col = k; }
      else if (k < 144)  col = 14 + (k - 16);
      if (gate != 3 && col >= 0) w = UWih[row * 142 + col];
    } else {
      if (gate != 2) w = UWhh[row * 128 + (k - 160)];
    }
    WTu[ck * 16384 + swz_idx(n, kk)] = f2u(w);
  } else if (b < 3312) {                // WBen1: 128x32 linear
    const int idx = (b - 3296) * 256 + t;
    const int n = (idx >> 5) & 127, kk = idx & 31;
    WBen1[idx] = f2u(kk < 14 ? EnW1[n * 14 + kk] : 0.f);
  } else if (b < 3376) {                // WBen2: 4*128*32 linear
    const int idx = (b - 3312) * 256 + t;
    const int ck = idx >> 12, n = (idx >> 5) & 127, kk = idx & 31;
    WBen2[idx] = f2u(EnW2[n * 128 + ck * 32 + kk]);
  } else if (b < 3392) {                // WBee1: 128x32 pair linear
    const int idx = (b - 3376) * 256 + t;
    const int n = (idx >> 5) & 127, kk = idx & 31;
    int col = (kk < 16) ? (kk < 14 ? kk : -1) : (kk < 30 ? 14 + (kk - 16) : -1);
    WBee1[idx] = f2u(col >= 0 ? EeW1[n * 28 + col] : 0.f);
    (void)n;
  } else if (b < 3456) {                // WBee2: 4*128*32 linear
    const int idx = (b - 3392) * 256 + t;
    const int ck = idx >> 12, n = (idx >> 5) & 127, kk = idx & 31;
    WBee2[idx] = f2u(EeW2[n * 128 + ck * 32 + kk]);
  } else if (b < 3458) {                // biasM [4 gates][128]
    const int idx = (b - 3456) * 256 + t;
    const int g = idx >> 7, c = idx & 127;
    float v;
    if (g == 0)      v = MBih[c] + MBhh[c];
    else if (g == 1) v = MBih[128 + c] + MBhh[128 + c];
    else if (g == 2) v = MBih[256 + c];
    else             v = MBhh[256 + c];
    biasM[idx] = v;
  } else if (b < 3460) {                // biasU
    const int idx = (b - 3458) * 256 + t;
    const int g = idx >> 7, c = idx & 127;
    float v;
    if (g == 0)      v = UBih[c] + UBhh[c];
    else if (g == 1) v = UBih[128 + c] + UBhh[128 + c];
    else if (g == 2) v = UBih[256 + c];
    else             v = UBhh[256 + c];
    biasU[idx] = v;
  } else if (b < 4228) {                // WT_G interleaved fp32: 384*512
    const int idx = (b - 3460) * 256 + t;
    const int kc = idx >> 9, cg = (idx >> 2) & 127, gate = idx & 3;
    const int row = (gate == 0) ? cg : (gate == 1) ? cg + 128 : cg + 256;
    float v = 0.f;
    if (kc < 256) { if (gate != 3) v = GWih[row * 256 + kc]; }
    else          { if (gate != 2) v = GWhh[row * 128 + (kc - 256)]; }
    WT_G[idx] = v;
  } else if (b < 4230) {                // biasG
    const int idx = (b - 4228) * 256 + t;
    const int cg = idx >> 2, gate = idx & 3;
    float v;
    if (gate == 0)      v = GBih[cg] + GBhh[cg];
    else if (gate == 1) v = GBih[cg + 128] + GBhh[cg + 128];
    else if (gate == 2) v = GBih[cg + 256];
    else                v = GBhh[cg + 256];
    biasG[idx] = v;
  } else {                              // bn2rep: [128][8] = bhh_n replicated
    const int idx = (b - 4230) * 256 + t;   // 1024
    bn2rep[idx] = f2u(MBhh[256 + (idx >> 3)]);
  }
}

// ---------------------------------------------------------------------------
// Shared pq phase: rows 64 (As5 = 5 chunks x [64][32] swizzled, xh k-layout
// padded to 160), cols 768 via 2 sequential halves, B direct-global WPQ.
// ---------------------------------------------------------------------------
DEV void pq_phase(ush* As5, const ush* __restrict__ WPQ,
                  const float* __restrict__ biasM, ush* __restrict__ PqT,
                  int rowBase, int lane, int w)
{
  const int quad = lane >> 4, l15 = lane & 15;
  for (int half = 0; half < 2; ++half) {
    f32x4 acc[6][4];
    #pragma unroll
    for (int tl = 0; tl < 6; ++tl)
      #pragma unroll
      for (int rt = 0; rt < 4; ++rt) {
        #pragma unroll
        for (int q = 0; q < 4; ++q) acc[tl][rt][q] = 0.f;
      }
    for (int ck = 0; ck < 5; ++ck) {
      s16x8 af[4];
      #pragma unroll
      for (int rt = 0; rt < 4; ++rt)
        af[rt] = *(const s16x8*)&As5[ck * 2048 + swz_blk(rt * 16 + l15, quad)];
      #pragma unroll
      for (int tl = 0; tl < 6; ++tl) {
        const int n = w * 96 + tl * 16 + l15;
        const s16x8 bf = *(const s16x8*)&WPQ[(ck * 768 + half * 384 + n) * 32 + quad * 8];
        #pragma unroll
        for (int rt = 0; rt < 4; ++rt) acc[tl][rt] = MFMA(af[rt], bf, acc[tl][rt]);
      }
    }
    #pragma unroll
    for (int tl = 0; tl < 6; ++tl) {
      const int col = w * 96 + tl * 16 + l15;
      const float bv = half ? 0.f : biasM[col];
      #pragma unroll
      for (int rt = 0; rt < 4; ++rt) {
        const int row0 = rowBase + rt * 16 + quad * 4;
        const int g = row0 >> 3, n0 = row0 & 7;
        u16x4 wv;
        #pragma unroll
        for (int q = 0; q < 4; ++q) wv[q] = f2u(acc[tl][rt][q] + bv);
        *(u16x4*)&PqT[((size_t)g * 768 + half * 384 + col) * 8 + n0] = wv;
      }
    }
  }
}

// stage towers (chunk0 kk0-15) + zero pad (chunk4 kk16-31) of As5; h-part
// (k 16..143) must be scattered by the caller's epilogue.
DEV void pq_stage_towers(ush* As5, const ush* __restrict__ xh, int rowBase, int t)
{
  const int gm = t >> 2, gb = t & 3, grow = rowBase + gm;
  if (gb < 2) {
    const s16x8 v = *(const s16x8*)(xh + grow * 144 + gb * 8);
    *(s16x8*)&As5[swz_blk(gm, gb)] = v;
  } else {
    *(s16x8*)&As5[4 * 2048 + swz_blk(gm, gb)] = z8();
  }
}

// ---------------------------------------------------------------------------
// Node encoder (E_n MLP) fused with initial P/Q GEMM. 64 node-rows per block.
// B weights direct-global (linear fragment layout).
// ---------------------------------------------------------------------------
__global__ __launch_bounds__(256, 2) void enc_en_pq(
    ush* __restrict__ xh,
    const ush* __restrict__ WB1, const float* __restrict__ b1,
    const ush* __restrict__ WB2, const float* __restrict__ b2,
    const ush* __restrict__ WPQ, const float* __restrict__ biasM,
    ush* __restrict__ PqT)
{
  __shared__ ush smem[10240];          // A1 [0,1024) | Z1 [1024,9216) ; As5 aliases [0,10240)
  ush* A1  = smem;
  ush* Z1  = smem + 1024;
  ush* As5 = smem;
  const int t = threadIdx.x, lane = t & 63, w = t >> 6;
  const int rowBase = blockIdx.x * 64;
  const int quad = lane >> 4, l15 = lane & 15;

  {
    const int gm = t >> 2, gb = t & 3, grow = rowBase + gm;
    s16x8 v = z8();
    if (gb < 2) v = *(const s16x8*)(xh + grow * 144 + gb * 8);
    *(s16x8*)&A1[swz_blk(gm, gb)] = v;
  }
  __syncthreads();

  // layer 1 (K=32)
  s16x8 af[4];
  #pragma unroll
  for (int rt = 0; rt < 4; ++rt)
    af[rt] = *(const s16x8*)&A1[swz_blk(rt * 16 + l15, quad)];
  f32x4 acc1[4][2];
  #pragma unroll
  for (int rt = 0; rt < 4; ++rt)
    #pragma unroll
    for (int ct = 0; ct < 2; ++ct) {
      #pragma unroll
      for (int q = 0; q < 4; ++q) acc1[rt][ct][q] = 0.f;
    }
  #pragma unroll
  for (int ct = 0; ct < 2; ++ct) {
    const int n = w * 32 + ct * 16 + l15;
    const s16x8 bf = *(const s16x8*)&WB1[n * 32 + quad * 8];
    #pragma unroll
    for (int rt = 0; rt < 4; ++rt) acc1[rt][ct] = MFMA(af[rt], bf, acc1[rt][ct]);
  }
  #pragma unroll
  for (int ct = 0; ct < 2; ++ct) {
    const int col = w * 32 + ct * 16 + l15;
    const int kk = col & 31;
    #pragma unroll
    for (int rt = 0; rt < 4; ++rt) {
      #pragma unroll
      for (int q = 0; q < 4; ++q) {
        const int m = rt * 16 + quad * 4 + q;
        Z1[w * 2048 + swz_idx(m, kk)] = f2u(tanh_f(acc1[rt][ct][q] + b1[col]));
      }
    }
  }
  __syncthreads();

  // layer 2 (K=128)
  f32x4 acc2[4][2];
  #pragma unroll
  for (int rt = 0; rt < 4; ++rt)
    #pragma unroll
    for (int ct = 0; ct < 2; ++ct) {
      #pragma unroll
      for (int q = 0; q < 4; ++q) acc2[rt][ct][q] = 0.f;
    }
  for (int ck2 = 0; ck2 < 4; ++ck2) {
    #pragma unroll
    for (int rt = 0; rt < 4; ++rt)
      af[rt] = *(const s16x8*)&Z1[ck2 * 2048 + swz_blk(rt * 16 + l15, quad)];
    #pragma unroll
    for (int ct = 0; ct < 2; ++ct) {
      const int n = w * 32 + ct * 16 + l15;
      const s16x8 bf = *(const s16x8*)&WB2[(ck2 * 128 + n) * 32 + quad * 8];
      #pragma unroll
      for (int rt = 0; rt < 4; ++rt) acc2[rt][ct] = MFMA(af[rt], bf, acc2[rt][ct]);
    }
  }
  __syncthreads();                     // Z1/A1 dead -> As5 alias safe

  // epilogue: h -> xh global + As5 scatter (k = 16+col)
  #pragma unroll
  for (int ct = 0; ct < 2; ++ct) {
    const int col = w * 32 + ct * 16 + l15;
    const int k = 16 + col, ck = k >> 5, kk = k & 31;
    #pragma unroll
    for (int rt = 0; rt < 4; ++rt) {
      #pragma unroll
      for (int q = 0; q < 4; ++q) {
        const int r = rt * 16 + quad * 4 + q;
        const ush hv = f2u(tanh_f(acc2[rt][ct][q] + b2[col]));
        xh[(rowBase + r) * 144 + 16 + col] = hv;
        As5[ck * 2048 + swz_idx(r, kk)] = hv;
      }
    }
  }
  pq_stage_towers(As5, xh, rowBase, t);
  __syncthreads();
  pq_phase(As5, WPQ, biasM, PqT, rowBase, lane, w);
}

// ---------------------------------------------------------------------------
// Edge GRU (transposed-C). FIRST: compute e_h^0 inline (Ee MLP) into As —
// e_h^0 never touches HBM. LAST: only store rows j==i+1 (sole consumers).
// ---------------------------------------------------------------------------
template<int FIRST, int LAST>
__global__ __launch_bounds__(256, 2) void edge_mfma(
    ush* __restrict__ eh, const ush* __restrict__ WTh,
    const ush* __restrict__ PqT, const ush* __restrict__ bn2rep,
    const ush* __restrict__ xh,
    const ush* __restrict__ WB1, const float* __restrict__ b1,
    const ush* __restrict__ WB2, const float* __restrict__ b2)
{
  __shared__ ush smem[FIRST ? 17408 : 8192];
  ush* As = smem;                      // e_h 64x128 swizzled (B operand + hp)
  const int t = threadIdx.x, lane = t & 63, w = t >> 6;
  const int g = blockIdx.x, rowBase = g * 64;
  const int quad = lane >> 4, l15 = lane & 15;

  if (FIRST) {
    ush* A1 = smem + 8192;
    ush* Z1 = smem + 9216;
    {
      const int gm = t >> 2, gb = t & 3;
      const int i = gm >> 3, j = gm & 7;
      const s16x8 v = (gb < 2) ? *(const s16x8*)(xh + (g * 8 + i) * 144 + gb * 8)
                               : *(const s16x8*)(xh + (g * 8 + j) * 144 + (gb - 2) * 8);
      *(s16x8*)&A1[swz_blk(gm, gb)] = v;
    }
    __syncthreads();
    s16x8 af[4];
    #pragma unroll
    for (int rt = 0; rt < 4; ++rt)
      af[rt] = *(const s16x8*)&A1[swz_blk(rt * 16 + l15, quad)];
    f32x4 acc1[4][2];
    #pragma unroll
    for (int rt = 0; rt < 4; ++rt)
      #pragma unroll
      for (int ct = 0; ct < 2; ++ct) {
        #pragma unroll
        for (int q = 0; q < 4; ++q) acc1[rt][ct][q] = 0.f;
      }
    #pragma unroll
    for (int ct = 0; ct < 2; ++ct) {
      const int n = w * 32 + ct * 16 + l15;
      const s16x8 bf = *(const s16x8*)&WB1[n * 32 + quad * 8];
      #pragma unroll
      for (int rt = 0; rt < 4; ++rt) acc1[rt][ct] = MFMA(af[rt], bf, acc1[rt][ct]);
    }
    #pragma unroll
    for (int ct = 0; ct < 2; ++ct) {
      const int col = w * 32 + ct * 16 + l15;
      const int kk = col & 31;
      #pragma unroll
      for (int rt = 0; rt < 4; ++rt) {
        #pragma unroll
        for (int q = 0; q < 4; ++q) {
          const int m = rt * 16 + quad * 4 + q;
          Z1[w * 2048 + swz_idx(m, kk)] = f2u(tanh_f(acc1[rt][ct][q] + b1[col]));
        }
      }
    }
    __syncthreads();
    f32x4 acc2[4][2];
    #pragma unroll
    for (int rt = 0; rt < 4; ++rt)
      #pragma unroll
      for (int ct = 0; ct < 2; ++ct) {
        #pragma unroll
        for (int q = 0; q < 4; ++q) acc2[rt][ct][q] = 0.f;
      }
    for (int ck2 = 0; ck2 < 4; ++ck2) {
      #pragma unroll
      for (int rt = 0; rt < 4; ++rt)
        af[rt] = *(const s16x8*)&Z1[ck2 * 2048 + swz_blk(rt * 16 + l15, quad)];
      #pragma unroll
      for (int ct = 0; ct < 2; ++ct) {
        const int n = w * 32 + ct * 16 + l15;
        const s16x8 bf = *(const s16x8*)&WB2[(ck2 * 128 + n) * 32 + quad * 8];
        #pragma unroll
        for (int rt = 0; rt < 4; ++rt) acc2[rt][ct] = MFMA(af[rt], bf, acc2[rt][ct]);
      }
    }
    // e_h^0 -> As (B-operand layout), no HBM round-trip
    #pragma unroll
    for (int ct = 0; ct < 2; ++ct) {
      const int col = w * 32 + ct * 16 + l15;
      const int kk = col & 31;
      #pragma unroll
      for (int rt = 0; rt < 4; ++rt) {
        #pragma unroll
        for (int q = 0; q < 4; ++q) {
          const int r = rt * 16 + quad * 4 + q;
          As[w * 2048 + swz_idx(r, kk)] = f2u(tanh_f(acc2[rt][ct][q] + b2[col]));
        }
      }
    }
  } else {
    const int gm = t >> 2, gb = t & 3;
    #pragma unroll
    for (int ck = 0; ck < 4; ++ck) {
      const s16x8 v = *(const s16x8*)(eh + (size_t)(rowBase + gm) * 128 + ck * 32 + gb * 8);
      *(s16x8*)&As[ck * 2048 + swz_blk(gm, gb)] = v;
    }
  }
  __syncthreads();

  f32x4 accR[2][4], accZ[2][4], accN1[2][4], accN2[2][4];
  #pragma unroll
  for (int mt = 0; mt < 2; ++mt)
    #pragma unroll
    for (int nt = 0; nt < 4; ++nt) {
      #pragma unroll
      for (int q = 0; q < 4; ++q) { accR[mt][nt][q] = 0.f; accZ[mt][nt][q] = 0.f; accN1[mt][nt][q] = 0.f; accN2[mt][nt][q] = 0.f; }
    }

  // h-phase: D += WTh · eh^T  (gates r, z, n2)
  #pragma unroll
  for (int ck = 0; ck < 4; ++ck) {
    s16x8 be[4];
    #pragma unroll
    for (int nt = 0; nt < 4; ++nt)
      be[nt] = *(const s16x8*)&As[ck * 2048 + swz_blk(nt * 16 + l15, quad)];
    #pragma unroll
    for (int mt = 0; mt < 2; ++mt) {
      const int nb = w * 32 + mt * 16 + l15;
      const int ko = quad * 8;
      const s16x8 aR = *(const s16x8*)&WTh[(ck * 384 + nb) * 32 + ko];
      const s16x8 aZ = *(const s16x8*)&WTh[(ck * 384 + 128 + nb) * 32 + ko];
      const s16x8 aN = *(const s16x8*)&WTh[(ck * 384 + 256 + nb) * 32 + ko];
      #pragma unroll
      for (int nt = 0; nt < 4; ++nt) {
        accR[mt][nt]  = MFMA(aR, be[nt], accR[mt][nt]);
        accZ[mt][nt]  = MFMA(aZ, be[nt], accZ[mt][nt]);
        accN2[mt][nt] = MFMA(aN, be[nt], accN2[mt][nt]);
      }
    }
  }

  // indicator chunk: A from PqT, B = in-register one-hot of (i, j)
  {
    s16x8 bI[4];
    #pragma unroll
    for (int nt = 0; nt < 4; ++nt) {
      const int erow = nt * 16 + l15;
      s16x8 v = z8();
      if (quad == 0)      v[erow >> 3] = (short)0x3F80;
      else if (quad == 1) v[erow & 7]  = (short)0x3F80;
      bI[nt] = v;
    }
    #pragma unroll
    for (int mt = 0; mt < 2; ++mt) {
      const int c = w * 32 + mt * 16 + l15;
      s16x8 aR = z8(), aZ = z8(), aN1 = z8(), aN2 = z8();
      if (quad == 0) {
        const ush* base = PqT + (size_t)g * 768 * 8;
        aR  = *(const s16x8*)&base[(c) * 8];
        aZ  = *(const s16x8*)&base[(128 + c) * 8];
        aN1 = *(const s16x8*)&base[(256 + c) * 8];
        aN2 = *(const s16x8*)&bn2rep[c * 8];
      } else if (quad == 1) {
        const ush* base = PqT + ((size_t)g * 768 + 384) * 8;
        aR  = *(const s16x8*)&base[(c) * 8];
        aZ  = *(const s16x8*)&base[(128 + c) * 8];
        aN1 = *(const s16x8*)&base[(256 + c) * 8];
      }
      #pragma unroll
      for (int nt = 0; nt < 4; ++nt) {
        accR[mt][nt]  = MFMA(aR,  bI[nt], accR[mt][nt]);
        accZ[mt][nt]  = MFMA(aZ,  bI[nt], accZ[mt][nt]);
        accN1[mt][nt] = MFMA(aN1, bI[nt], accN1[mt][nt]);
        accN2[mt][nt] = MFMA(aN2, bI[nt], accN2[mt][nt]);
      }
    }
  }

  // epilogue
  #pragma unroll
  for (int mt = 0; mt < 2; ++mt) {
    const int hc0 = w * 32 + mt * 16 + quad * 4;
    const int ck2 = hc0 >> 5, kkB = hc0 & 31;
    #pragma unroll
    for (int nt = 0; nt < 4; ++nt) {
      const int erow = nt * 16 + l15;
      if (LAST && (erow & 7) != (erow >> 3) + 1) continue;   // only j==i+1 consumed
      const u16x4 hp4 = *(const u16x4*)&As[ck2 * 2048 + swz_blk(erow, kkB >> 3) + (kkB & 7)];
      u16x4 ov;
      #pragma unroll
      for (int q = 0; q < 4; ++q) {
        const float rg = sigmoid_f(accR[mt][nt][q]);
        const float zg = sigmoid_f(accZ[mt][nt][q]);
        const float nn = tanh_f(accN1[mt][nt][q] + rg * accN2[mt][nt][q]);
        const float hp = u2f(hp4[q]);
        ov[q] = f2u(nn + zg * (hp - nn));
      }
      *(u16x4*)&eh[(size_t)(rowBase + erow) * 128 + hc0] = ov;
    }
  }
}

// ---------------------------------------------------------------------------
// Node GRU fused with P/Q GEMM for the next iteration (PQ=0 on last iter).
// ---------------------------------------------------------------------------
template<int PQ>
__global__ __launch_bounds__(256, 2) void gru_node_pq(
    ush* __restrict__ xh, const ush* __restrict__ eh,
    const ush* __restrict__ WT, const float* __restrict__ bias,
    const ush* __restrict__ WPQ, const float* __restrict__ biasM,
    ush* __restrict__ PqT)
{
  constexpr int NCH = 9, XCH = 5;
  __shared__ ush smem[17408];          // As [0,1024) | Bs [1024,17408) ; As5 aliases Bs
  ush* As  = smem;
  ush* Bs  = smem + 1024;
  ush* As5 = smem + 1024;
  const int t = threadIdx.x, lane = t & 63, w = t >> 6;
  const int rowBase = blockIdx.x * 64;
  const int gm = t >> 2, gb = t & 3, grow = rowBase + gm;

  f32x4 accR[4][2], accZ[4][2], accN1[4][2], accN2[4][2];
  #pragma unroll
  for (int rt = 0; rt < 4; ++rt)
    #pragma unroll
    for (int s = 0; s < 2; ++s) {
      #pragma unroll
      for (int q = 0; q < 4; ++q) { accR[rt][s][q] = 0.f; accZ[rt][s][q] = 0.f; accN1[rt][s][q] = 0.f; accN2[rt][s][q] = 0.f; }
    }

  for (int ck = 0; ck < NCH; ++ck) {
    const ush* wsrc = WT + ck * 16384;
    #pragma unroll
    for (int ii = 0; ii < 8; ++ii) {
      const int o = (t + ii * 256) * 8;
      *(s16x8*)&Bs[o] = *(const s16x8*)&wsrc[o];
    }
    {
      const int k0 = ck * 32 + gb * 8;
      s16x8 v = z8();
      if (k0 < 16)       v = *(const s16x8*)(xh + grow * 144 + k0);
      else if (k0 < 144) {
        const int i = grow & 7;
        if (i < 7) v = *(const s16x8*)(eh + (size_t)(grow * 8 + i + 1) * 128 + (k0 - 16));
      } else if (k0 >= 160) {
        v = *(const s16x8*)(xh + grow * 144 + 16 + (k0 - 160));
      }
      *(s16x8*)&As[swz_blk(gm, gb)] = v;
    }
    __syncthreads();

    s16x8 af[4];
    #pragma unroll
    for (int rt = 0; rt < 4; ++rt)
      af[rt] = *(const s16x8*)&As[swz_blk(rt * 16 + (lane & 15), lane >> 4)];
    if (ck < XCH) {
      #pragma unroll
      for (int s = 0; s < 2; ++s) {
        const int nb = w * 32 + s * 16 + (lane & 15);
        const s16x8 bR = *(const s16x8*)&Bs[swz_blk(0 * 128 + nb, lane >> 4)];
        const s16x8 bZ = *(const s16x8*)&Bs[swz_blk(1 * 128 + nb, lane >> 4)];
        const s16x8 bN = *(const s16x8*)&Bs[swz_blk(2 * 128 + nb, lane >> 4)];
        #pragma unroll
        for (int rt = 0; rt < 4; ++rt) {
          accR[rt][s]  = MFMA(af[rt], bR, accR[rt][s]);
          accZ[rt][s]  = MFMA(af[rt], bZ, accZ[rt][s]);
          accN1[rt][s] = MFMA(af[rt], bN, accN1[rt][s]);
        }
      }
    } else {
      #pragma unroll
      for (int s = 0; s < 2; ++s) {
        const int nb = w * 32 + s * 16 + (lane & 15);
        const s16x8 bR = *(const s16x8*)&Bs[swz_blk(0 * 128 + nb, lane >> 4)];
        const s16x8 bZ = *(const s16x8*)&Bs[swz_blk(1 * 128 + nb, lane >> 4)];
        const s16x8 bN = *(const s16x8*)&Bs[swz_blk(3 * 128 + nb, lane >> 4)];
        #pragma unroll
        for (int rt = 0; rt < 4; ++rt) {
          accR[rt][s]  = MFMA(af[rt], bR, accR[rt][s]);
          accZ[rt][s]  = MFMA(af[rt], bZ, accZ[rt][s]);
          accN2[rt][s] = MFMA(af[rt], bN, accN2[rt][s]);
        }
      }
    }
    __syncthreads();
  }

  // epilogue: write h to xh; if PQ also scatter into As5 (aliases Bs — safe,
  // last Bs read was before the loop-final barrier)
  #pragma unroll
  for (int s = 0; s < 2; ++s) {
    const int hcol = w * 32 + s * 16 + (lane & 15);
    const float bR = bias[hcol], bZ = bias[128 + hcol], bN1 = bias[256 + hcol], bN2 = bias[384 + hcol];
    const int k = 16 + hcol, ckh = k >> 5, kkh = k & 31;
    #pragma unroll
    for (int rt = 0; rt < 4; ++rt) {
      #pragma unroll
      for (int q = 0; q < 4; ++q) {
        const int r = rt * 16 + (lane >> 4) * 4 + q;
        const int row = rowBase + r;
        const float hp = u2f(xh[row * 144 + 16 + hcol]);
        const float rg = sigmoid_f(accR[rt][s][q] + bR);
        const float zg = sigmoid_f(accZ[rt][s][q] + bZ);
        const float nn = tanh_f(accN1[rt][s][q] + bN1 + rg * (accN2[rt][s][q] + bN2));
        const ush hv = f2u(nn + zg * (hp - nn));
        xh[row * 144 + 16 + hcol] = hv;
        if (PQ) As5[ckh * 2048 + swz_idx(r, kkh)] = hv;
      }
    }
  }
  if (PQ) {
    pq_stage_towers(As5, xh, rowBase, t);
    __syncthreads();
    pq_phase(As5, WPQ, biasM, PqT, rowBase, lane, w);
  }
}

// ---------------------------------------------------------------------------
// readout path
// ---------------------------------------------------------------------------
__global__ __launch_bounds__(256) void sums2(const ush* __restrict__ xh, const ush* __restrict__ eh,
                                             float* __restrict__ hsum, float* __restrict__ esum) {
  const int idx = blockIdx.x * 256 + threadIdx.x;    // 4096*128
  const int n = idx >> 7, hh = idx & 127;
  float hs = 0.f, es = 0.f;
  #pragma unroll
  for (int i = 0; i < 8; ++i) hs += u2f(xh[(n * 8 + i) * 144 + 16 + hh]);
  #pragma unroll
  for (int i = 0; i < 7; ++i) es += u2f(eh[(size_t)((n * 8 + i) * 8 + i + 1) * 128 + hh]);
  hsum[idx] = hs;
  esum[idx] = es;
}

// global GRU (h_prev = 0) fused with output head: 16 graphs per block.
__global__ __launch_bounds__(256) void gru_global_out(
    const float* __restrict__ hsum, const float* __restrict__ esum,
    const float* __restrict__ WT, const float* __restrict__ bias,
    const float* __restrict__ OW, const float* __restrict__ Ob,
    float* __restrict__ out)
{
  constexpr int KT = 384;
  __shared__ float4 ATl4[KT * 4];
  __shared__ float4 Bl4[16 * 128];
  __shared__ float gmat[16 * 128];
  __shared__ float red[16 * 4];
  float* ATl = (float*)ATl4;
  const int t = threadIdx.x;
  const int rowBase = blockIdx.x * 16;
  for (int idx = t; idx < KT * 16; idx += 256) {
    const int kc = idx >> 4, r = idx & 15, grow = rowBase + r;
    float v = 0.f;
    if (kc < 128)      v = hsum[grow * 128 + kc];
    else if (kc < 256) v = esum[grow * 128 + (kc - 128)];
    ATl[idx] = v;
  }
  const int c = t & 127, rh = t >> 7;
  float accR[8], accZ[8], accN1[8];
  #pragma unroll
  for (int rr = 0; rr < 8; ++rr) { accR[rr] = 0.f; accZ[rr] = 0.f; accN1[rr] = 0.f; }
  const float4* WT4 = (const float4*)WT;
  for (int ck = 0; ck < 16; ++ck) {
    __syncthreads();
    #pragma unroll
    for (int ii = 0; ii < 8; ++ii) { const int idx = t + ii * 256; Bl4[idx] = WT4[ck * 2048 + idx]; }
    __syncthreads();
    const int kb = ck * 16;
    #pragma unroll
    for (int kcl = 0; kcl < 16; ++kcl) {
      const float4 wv = Bl4[kcl * 128 + c];
      const float4 a0 = ATl4[(kb + kcl) * 4 + rh * 2];
      const float4 a1 = ATl4[(kb + kcl) * 4 + rh * 2 + 1];
      const float av[8] = {a0.x, a0.y, a0.z, a0.w, a1.x, a1.y, a1.z, a1.w};
      #pragma unroll
      for (int rr = 0; rr < 8; ++rr) {
        accR[rr]  += wv.x * av[rr];
        accZ[rr]  += wv.y * av[rr];
        accN1[rr] += wv.z * av[rr];
      }
    }
  }
  const float4 bb = ((const float4*)bias)[c];
  const float ow = OW[c];
  #pragma unroll
  for (int rr = 0; rr < 8; ++rr) {
    const float rg = sigmoid_f(accR[rr] + bb.x);
    const float zg = sigmoid_f(accZ[rr] + bb.y);
    const float nn = tanh_f(accN1[rr] + bb.z + rg * bb.w);
    gmat[(rh * 8 + rr) * 128 + c] = (1.f - zg) * nn * ow;
  }
  __syncthreads();
  if (t < 64) {
    const int r = t >> 2, part = t & 3;
    float s = 0.f;
    #pragma unroll
    for (int cc = 0; cc < 32; ++cc) s += gmat[r * 128 + part * 32 + cc];
    red[r * 4 + part] = s;
  }
  __syncthreads();
  if (t < 16) {
    const float s = red[t * 4] + red[t * 4 + 1] + red[t * 4 + 2] + red[t * 4 + 3];
    out[rowBase + t] = sigmoid_f(s + Ob[0]);
  }
}

// ---------------------------------------------------------------------------
extern "C" void kernel_launch(void* const* d_in, const int* in_sizes, int n_in,
                              void* d_out, int out_size, void* d_ws, size_t ws_size,
                              hipStream_t stream)
{
  (void)in_sizes; (void)n_in; (void)out_size; (void)ws_size;
  const float* towers = (const float*)d_in[0];
  const float* EnW1 = (const float*)d_in[1];
  const float* EnB1 = (const float*)d_in[2];
  const float* EnW2 = (const float*)d_in[3];
  const float* EnB2 = (const float*)d_in[4];
  const float* EeW1 = (const float*)d_in[5];
  const float* EeB1 = (const float*)d_in[6];
  const float* EeW2 = (const float*)d_in[7];
  const float* EeB2 = (const float*)d_in[8];
  const float* UWih = (const float*)d_in[9];
  const float* UWhh = (const float*)d_in[10];
  const float* UBih = (const float*)d_in[11];
  const float* UBhh = (const float*)d_in[12];
  const float* MWih = (const float*)d_in[13];
  const float* MWhh = (const float*)d_in[14];
  const float* MBih = (const float*)d_in[15];
  const float* MBhh = (const float*)d_in[16];
  const float* GWih = (const float*)d_in[17];
  const float* GWhh = (const float*)d_in[18];
  const float* GBih = (const float*)d_in[19];
  const float* GBhh = (const float*)d_in[20];
  const float* OW   = (const float*)d_in[21];
  const float* Ob   = (const float*)d_in[22];

  char* ws = (char*)d_ws;
  size_t off = 0;
  auto take = [&](size_t b) { void* p = ws + off; off = (off + b + 255) & ~(size_t)255; return p; };
  ush*   xh     = (ush*)take((size_t)32768 * 144 * 2);
  ush*   eh     = (ush*)take((size_t)262144 * 128 * 2);
  ush*   PqT    = (ush*)take((size_t)4096 * 768 * 8 * 2);
  float* hsum   = (float*)take((size_t)4096 * 128 * 4);
  float* esum   = (float*)take((size_t)4096 * 128 * 4);
  ush*   WPQ    = (ush*)take((size_t)5 * 768 * 32 * 2);
  ush*   WTh    = (ush*)take((size_t)4 * 384 * 32 * 2);
  ush*   WTu    = (ush*)take((size_t)9 * 512 * 32 * 2);
  ush*   WBen1  = (ush*)take((size_t)128 * 32 * 2);
  ush*   WBen2  = (ush*)take((size_t)4 * 128 * 32 * 2);
  ush*   WBee1  = (ush*)take((size_t)128 * 32 * 2);
  ush*   WBee2  = (ush*)take((size_t)4 * 128 * 32 * 2);
  float* biasM  = (float*)take(512 * 4);
  float* biasU  = (float*)take(512 * 4);
  float* WT_G   = (float*)take((size_t)384 * 512 * 4);
  float* biasG  = (float*)take(512 * 4);
  ush*   bn2rep = (ush*)take(128 * 8 * 2);

  prep_all<<<4234, 256, 0, stream>>>(
      towers, MWih, MWhh, UWih, UWhh, EnW1, EnW2, EeW1, EeW2,
      MBih, MBhh, UBih, UBhh, GWih, GWhh, GBih, GBhh,
      xh, WPQ, WTh, WTu, WBen1, WBen2, WBee1, WBee2,
      biasM, biasU, WT_G, biasG, bn2rep);

  // node encoder + initial P/Q
  enc_en_pq<<<512, 256, 0, stream>>>(xh, WBen1, EnB1, WBen2, EnB2, WPQ, biasM, PqT);

  // it 0: edge computes e_h^0 inline (Ee MLP) then GRU
  edge_mfma<1, 0><<<4096, 256, 0, stream>>>(eh, WTh, PqT, bn2rep, xh, WBee1, EeB1, WBee2, EeB2);
  gru_node_pq<1><<<512, 256, 0, stream>>>(xh, eh, WTu, biasU, WPQ, biasM, PqT);
  // it 1
  edge_mfma<0, 0><<<4096, 256, 0, stream>>>(eh, WTh, PqT, bn2rep, xh, WBee1, EeB1, WBee2, EeB2);
  gru_node_pq<1><<<512, 256, 0, stream>>>(xh, eh, WTu, biasU, WPQ, biasM, PqT);
  // it 2: edge stores only consumed rows; node skips P/Q
  edge_mfma<0, 1><<<4096, 256, 0, stream>>>(eh, WTh, PqT, bn2rep, xh, WBee1, EeB1, WBee2, EeB2);
  gru_node_pq<0><<<512, 256, 0, stream>>>(xh, eh, WTu, biasU, WPQ, biasM, PqT);

  // readout
  sums2<<<2048, 256, 0, stream>>>(xh, eh, hsum, esum);
  gru_global_out<<<256, 256, 0, stream>>>(hsum, esum, WT_G, biasG, OW, Ob, (float*)d_out);
}